// Round 9
// baseline (10124.551 us; speedup 1.0000x reference)
//
#include <hip/hip_runtime.h>

#define BATCH 1024
#define SEQ 512
#define NFEAT 24
#define NCELL 512
#define ZC 2048      // 4*NCELL
#define KP 544       // reordered K: [h(512) | x(24) | pad(8)]
#define NCH 17       // K chunks of 32
#define KL 576       // LDS k-stride in u16 (XOR-swizzled in 16B units)
#define DENSE_N 2048
#define PRED_N 576
#define NWG 256
#define NGRP 8       // row groups (128 rows each)
#define GWG 32       // WGs per group

typedef unsigned short u16;
typedef unsigned int u32;
typedef unsigned long long u64;
typedef unsigned short u16x8 __attribute__((ext_vector_type(8)));
typedef short s16x8 __attribute__((ext_vector_type(8)));
typedef u32 u32x4 __attribute__((ext_vector_type(4)));
typedef float f32x4 __attribute__((ext_vector_type(4)));

__device__ __forceinline__ float sigm(float x) { return 1.f / (1.f + __expf(-x)); }
__device__ __forceinline__ float ftanh(float x) {
    float t = __expf(-2.f * fabsf(x));
    float r = (1.f - t) / (1.f + t);
    return copysignf(r, x);
}
__device__ __forceinline__ u16 f2b(float v) {           // f32 -> bf16 RTNE
    unsigned int x = __float_as_uint(v);
    unsigned int r = (x + 0x7fffu + ((x >> 16) & 1u)) >> 16;
    return (u16)r;
}
__device__ __forceinline__ float b2f(u16 u) { return __uint_as_float(((unsigned int)u) << 16); }

// Fragment-major H layout. u64 index: (((rb*4+wv)*NCH + ch)*8 + m*4 + i)*64 + lane.
__device__ __forceinline__ u32 hword(int row, int k) {
    int rb = row >> 7, wv = (row >> 5) & 3, m = (row >> 4) & 1, rl = row & 15;
    int ch = k >> 5, sub = (k & 31) >> 3, i = (k & 7) >> 1, w = k & 1;
    u32 q = (u32)(((rb * 4 + wv) * NCH + ch) * 8 + m * 4 + i) * 64u + (u32)(rl + (sub << 4));
    return q * 2u + (u32)w;
}

// unpack 8 packed cells (lo16=hi-plane bf16, hi16=lo-plane bf16) into two s16x8
__device__ __forceinline__ void unpack16(const u32x4 a, const u32x4 b, s16x8* hi, s16x8* lo) {
    u32* h = (u32*)hi; u32* l = (u32*)lo;
    h[0] = __builtin_amdgcn_perm(a[1], a[0], 0x05040100u);
    h[1] = __builtin_amdgcn_perm(a[3], a[2], 0x05040100u);
    h[2] = __builtin_amdgcn_perm(b[1], b[0], 0x05040100u);
    h[3] = __builtin_amdgcn_perm(b[3], b[2], 0x05040100u);
    l[0] = __builtin_amdgcn_perm(a[1], a[0], 0x07060302u);
    l[1] = __builtin_amdgcn_perm(a[3], a[2], 0x07060302u);
    l[2] = __builtin_amdgcn_perm(b[1], b[0], 0x07060302u);
    l[3] = __builtin_amdgcn_perm(b[3], b[2], 0x07060302u);
}

// ---- probe primitives (exact cache-bit control) ----
__device__ __forceinline__ u32 probe_load_plain(const u32* p) {
    u32 v;
    asm volatile("global_load_dword %0, %1, off\n\ts_waitcnt vmcnt(0)"
                 : "=v"(v) : "v"(p) : "memory");
    return v;
}
__device__ __forceinline__ u32 probe_load_sc0(const u32* p) {
    u32 v;
    asm volatile("global_load_dword %0, %1, off sc0\n\ts_waitcnt vmcnt(0)"
                 : "=v"(v) : "v"(p) : "memory");
    return v;
}
__device__ __forceinline__ void probe_store_plain(u32* p, u32 v) {
    asm volatile("global_store_dword %0, %1, off\n\ts_waitcnt vmcnt(0)"
                 :: "v"(p), "v"(v) : "memory");
}

// group barrier helper (tid0 only), one-shot epochs
__device__ __forceinline__ void grp_bar(int* cnt, int* ep, int target) {
    int n = __hip_atomic_fetch_add(cnt, 1, __ATOMIC_RELAXED, __HIP_MEMORY_SCOPE_AGENT);
    if (n == GWG - 1) {
        __hip_atomic_store(ep, target, __ATOMIC_RELEASE, __HIP_MEMORY_SCOPE_AGENT);
    } else {
        int spins = 0;
        while (__hip_atomic_load(ep, __ATOMIC_RELAXED, __HIP_MEMORY_SCOPE_AGENT) < target) {
            __builtin_amdgcn_s_sleep(2);
            if (++spins > 20000000) break;
        }
    }
}

// ---------- prep: W -> transposed, K-reordered, split hi/lo ----------
__global__ __launch_bounds__(256) void prep_w(const float* __restrict__ W,
                                              u16* __restrict__ Whi, u16* __restrict__ Wlo) {
    int o = blockIdx.x * 256 + threadIdx.x;            // over ZC*KP
    if (o >= ZC * KP) return;
    int n = o / KP, k = o % KP;
    float v = 0.f;
    if (k < NCELL)              v = W[(size_t)(NFEAT + k) * ZC + n];   // h rows
    else if (k < NCELL + NFEAT) v = W[(size_t)(k - NCELL) * ZC + n];   // x rows
    u16 hi = f2b(v);
    u16 lo = f2b(v - b2f(hi));
    Whi[o] = hi; Wlo[o] = lo;
}

// ---------- prep: H0 = [h=0 | x_0 | pad=0], H1 = 0 (fragment-major packed u32) ----------
__global__ __launch_bounds__(256) void prep_h(const float* __restrict__ X,
                                              u32* __restrict__ H0, u32* __restrict__ H1) {
    int o = blockIdx.x * 256 + threadIdx.x;            // over BATCH*KP
    if (o >= BATCH * KP) return;
    int row = o / KP, k = o % KP;
    u32 pk = 0;
    if (k >= NCELL && k < NCELL + NFEAT) {
        float v = X[(size_t)row * (SEQ * NFEAT) + (k - NCELL)];  // t = 0
        u16 hi = f2b(v), lo = f2b(v - b2f(hi));
        pk = (u32)hi | ((u32)lo << 16);
    }
    u32 w = hword(row, k);
    H0[w] = pk;
    H1[w] = 0;
}

// ---------- persistent LSTM ----------
// Per-group runtime coherence probe selects:
//   fast: plain write-back stores + sc0 (XCD-L2) loads, counted vmcnt pipeline
//   slow: round-8 agent read/write-through path (placement-independent)
__global__ __launch_bounds__(256, 1) void lstm_persist(
    u32* __restrict__ H0, u32* __restrict__ H1,
    const u16* __restrict__ Wthi, const u16* __restrict__ Wtlo,  // [ZC][KP]
    const float* __restrict__ bias,                              // [ZC]
    const float* __restrict__ X,                                 // [BATCH][SEQ][NFEAT]
    float* __restrict__ hf32,                                    // [BATCH][NCELL]
    int* __restrict__ bar,                                       // 8 x 64 ints
    u32* __restrict__ cells)                                     // 8 x 32 x 16 u32
{
    extern __shared__ u16 Ws[];   // [2 planes][64 cols][KL], XOR-swizzled

    const int tid = (int)threadIdx.x;
    const int bid = (int)blockIdx.x;
    const int rb = bid & 7, nb = bid >> 3;
    const int r0 = rb * 128;
    const int lane = tid & 63, wv = tid >> 6;
    int* __restrict__ bcnt   = bar + rb * 64;
    int* __restrict__ bepoch = bar + rb * 64 + 32;

    // ---- load W slice into LDS once (swizzled) ----
    #pragma unroll
    for (int p = 0; p < 2; ++p) {
        const u16* Wp = p ? Wtlo : Wthi;
        for (int e = tid; e < 64 * (KP / 8); e += 256) {
            int col = e / (KP / 8), k8 = (e % (KP / 8)) * 8;
            int zc = (col >> 4) * NCELL + nb * 16 + (col & 15);
            int so = k8 ^ ((col & 7) << 3);
            *(u16x8*)&Ws[(p * 64 + col) * KL + so] = *(const u16x8*)&Wp[(size_t)zc * KP + k8];
        }
    }
    __syncthreads();

    // ---- runtime XCD-coherence probe (per group) ----
    __shared__ int s_fast;
    {
        int* pcntA = bar + rb * 64 + 1;
        int* pepA  = bar + rb * 64 + 33;
        int* pcntB = bar + rb * 64 + 2;
        int* pepB  = bar + rb * 64 + 34;
        int* pcntC = bar + rb * 64 + 3;
        int* pepC  = bar + rb * 64 + 35;
        int* pbad  = bar + rb * 64 + 36;
        u32* mycell = cells + (rb * 32 + nb) * 16;
        int w = (nb + 1 + tid) % 32;
        u32* pcell = cells + (rb * 32 + w) * 16;
        if (tid < 31) (void)probe_load_plain(pcell);   // warm: clean 0 line into L1+L2
        __syncthreads();
        if (tid == 0) grp_bar(pcntA, pepA, 1);         // all warms done
        __syncthreads();
        if (tid == 0) probe_store_plain(mycell, 1u);   // dirty 1 into MY L2
        if (tid == 0) grp_bar(pcntB, pepB, 1);         // all stores done
        __syncthreads();
        u32 chk = 1;
        if (tid < 31) chk = probe_load_sc0(pcell);     // same L2 -> 1; cross-XCD -> stale 0
        if (tid < 31 && chk != 1u)
            __hip_atomic_fetch_or(pbad, 1, __ATOMIC_RELAXED, __HIP_MEMORY_SCOPE_AGENT);
        __syncthreads();
        if (tid == 0) {
            grp_bar(pcntC, pepC, 1);
            s_fast = (__hip_atomic_load(pbad, __ATOMIC_RELAXED, __HIP_MEMORY_SCOPE_AGENT) == 0) ? 1 : 0;
        }
        __syncthreads();
    }
    const bool fastf = (s_fast != 0);

    const int cell = nb * 16 + (lane & 15);
    const float bi = bias[cell], bj = bias[NCELL + cell];
    const float bf_ = bias[2 * NCELL + cell], bo = bias[3 * NCELL + cell];

    const int akof = (lane >> 4) * 8;                 // k sub-offset for B frags (u16)
    const u32 wbase = (u32)((rb * 4 + wv) * NCH) * 512u + (u32)lane;

    // epilogue store constants
    const int cellch = nb >> 1;
    const int cellsub = ((nb & 1) << 1) + ((lane & 15) >> 3);
    const int celli = (lane & 7) >> 1;
    const int cellw = lane & 1;
    const u32 ebase = (u32)((rb * 4 + wv) * NCH + cellch) * 512u;

    float ct[2][4] = {};   // persistent cell state in registers

    for (int t = 0; t < SEQ; ++t) {
        const u64* Hq = (const u64*)((t & 1) ? H1 : H0);
        u32*       Np = (t & 1) ? H0 : H1;

        f32x4 acc[2][4] = {};   // [m][gate]
        u64 fr[3][8];           // A triple buffer: [buf][m*4+i]

#define ALOADS(f, ch) do { \
        _Pragma("unroll") \
        for (int m_ = 0; m_ < 2; ++m_) \
            _Pragma("unroll") \
            for (int i_ = 0; i_ < 4; ++i_) \
                f[m_ * 4 + i_] = __hip_atomic_load( \
                    &Hq[wbase + (u32)(ch) * 512u + (u32)m_ * 256u + (u32)i_ * 64u], \
                    __ATOMIC_RELAXED, __HIP_MEMORY_SCOPE_AGENT); } while (0)
#define ALOADF(f, ch) do { \
        _Pragma("unroll") \
        for (int m_ = 0; m_ < 2; ++m_) \
            _Pragma("unroll") \
            for (int i_ = 0; i_ < 4; ++i_) { \
                const u64* ap_ = &Hq[wbase + (u32)(ch) * 512u + (u32)m_ * 256u + (u32)i_ * 64u]; \
                asm volatile("global_load_dwordx2 %0, %1, off sc0" \
                             : "=v"(f[m_ * 4 + i_]) : "v"(ap_)); \
            } } while (0)
#define WAITV(n) do { asm volatile("s_waitcnt vmcnt(" #n ")" ::: "memory"); \
                      __builtin_amdgcn_sched_barrier(0); } while (0)
#define WSOFF(cb, off) ((cb) * KL + (((off)) ^ (((cb) & 7) << 3)))
#define CCOMP(f, ch) do { \
        s16x8 ah0, al0, ah1, al1; \
        unpack16(*(const u32x4*)&f[0], *(const u32x4*)&f[2], &ah0, &al0); \
        unpack16(*(const u32x4*)&f[4], *(const u32x4*)&f[6], &ah1, &al1); \
        s16x8 bh[4], bl[4]; \
        _Pragma("unroll") \
        for (int n = 0; n < 4; ++n) { \
            bh[n] = *(const s16x8*)&Ws[WSOFF(n * 16 + (lane & 15), (ch) * 32 + akof)]; \
            bl[n] = *(const s16x8*)&Ws[WSOFF(64 + n * 16 + (lane & 15), (ch) * 32 + akof)]; \
        } \
        _Pragma("unroll") \
        for (int n = 0; n < 4; ++n) { \
            acc[0][n] = __builtin_amdgcn_mfma_f32_16x16x32_bf16(ah0, bh[n], acc[0][n], 0, 0, 0); \
            acc[0][n] = __builtin_amdgcn_mfma_f32_16x16x32_bf16(ah0, bl[n], acc[0][n], 0, 0, 0); \
            acc[0][n] = __builtin_amdgcn_mfma_f32_16x16x32_bf16(al0, bh[n], acc[0][n], 0, 0, 0); \
            acc[1][n] = __builtin_amdgcn_mfma_f32_16x16x32_bf16(ah1, bh[n], acc[1][n], 0, 0, 0); \
            acc[1][n] = __builtin_amdgcn_mfma_f32_16x16x32_bf16(ah1, bl[n], acc[1][n], 0, 0, 0); \
            acc[1][n] = __builtin_amdgcn_mfma_f32_16x16x32_bf16(al1, bh[n], acc[1][n], 0, 0, 0); \
        } } while (0)

        if (fastf) {
            ALOADF(fr[0], 0); ALOADF(fr[1], 1);
            #pragma unroll
            for (int ch = 0; ch < NCH; ++ch) {
                if (ch + 2 < NCH)      { ALOADF(fr[(ch + 2) % 3], ch + 2); WAITV(16); }
                else if (ch + 1 < NCH) { WAITV(8); }
                else                   { WAITV(0); }
                CCOMP(fr[ch % 3], ch);
            }
        } else {
            ALOADS(fr[0], 0); ALOADS(fr[1], 1);
            #pragma unroll
            for (int ch = 0; ch < NCH; ++ch) {
                if (ch + 2 < NCH) ALOADS(fr[(ch + 2) % 3], ch + 2);
                CCOMP(fr[ch % 3], ch);
            }
        }
#undef ALOADS
#undef ALOADF
#undef CCOMP

        // Fused gate epilogue; c in registers. TF gate order: i, j, f, o.
        u32 pkv[2][4];
        u32 qq[2][4];
        #pragma unroll
        for (int m = 0; m < 2; ++m) {
            #pragma unroll
            for (int r = 0; r < 4; ++r) {
                int row = r0 + wv * 32 + m * 16 + (lane >> 4) * 4 + r;
                float zi = acc[m][0][r] + bi;
                float zj = acc[m][1][r] + bj;
                float zf = acc[m][2][r] + bf_;
                float zo = acc[m][3][r] + bo;
                float cn = ct[m][r] * sigm(zf + 1.0f) + sigm(zi) * ftanh(zj);
                ct[m][r] = cn;
                float h = ftanh(cn) * sigm(zo);
                u16 hh = f2b(h);
                u16 hl = f2b(h - b2f(hh));
                pkv[m][r] = (u32)hh | ((u32)hl << 16);
                int lp = ((lane >> 4) << 2) + r + (cellsub << 4);
                u32 q = ebase + (u32)(m * 256 + celli * 64 + lp);
                qq[m][r] = q * 2u + (u32)cellw;
                if (t == SEQ - 1) hf32[(size_t)row * NCELL + cell] = h;
            }
        }
        if (fastf) {
            #pragma unroll
            for (int m = 0; m < 2; ++m)
                #pragma unroll
                for (int r = 0; r < 4; ++r)
                    Np[qq[m][r]] = pkv[m][r];
        } else {
            #pragma unroll
            for (int m = 0; m < 2; ++m)
                #pragma unroll
                for (int r = 0; r < 4; ++r)
                    __hip_atomic_store(&Np[qq[m][r]], pkv[m][r],
                                       __ATOMIC_RELAXED, __HIP_MEMORY_SCOPE_AGENT);
        }
        // Stage next step's x-slice into the next A plane (fragment-major).
        if (t + 1 < SEQ && nb < NFEAT && tid < 128) {
            int row = r0 + tid;
            float v = X[(size_t)row * (SEQ * NFEAT) + (t + 1) * NFEAT + nb];
            u16 vh = f2b(v), vl = f2b(v - b2f(vh));
            u32 pk = (u32)vh | ((u32)vl << 16);
            int wv2 = tid >> 5, m2 = (tid >> 4) & 1;
            int lp = (tid & 15) + ((nb >> 3) << 4);
            u32 q = (u32)((rb * 4 + wv2) * NCH + 16) * 512u
                  + (u32)(m2 * 256 + ((nb & 7) >> 1) * 64 + lp);
            u32 qx = q * 2u + (u32)(nb & 1);
            if (fastf) Np[qx] = pk;
            else __hip_atomic_store(&Np[qx], pk, __ATOMIC_RELAXED, __HIP_MEMORY_SCOPE_AGENT);
        }

        // ---- row-group barrier: pure atomics, NO cache maintenance ----
        __syncthreads();   // vmcnt drained: stores visible at their coherence point
        if (tid == 0) {
            int n = __hip_atomic_fetch_add(bcnt, 1, __ATOMIC_RELAXED, __HIP_MEMORY_SCOPE_AGENT);
            if (n == GWG - 1) {
                __hip_atomic_store(bcnt, 0, __ATOMIC_RELAXED, __HIP_MEMORY_SCOPE_AGENT);
                __hip_atomic_store(bepoch, t + 1, __ATOMIC_RELEASE, __HIP_MEMORY_SCOPE_AGENT);
            } else {
                int spins = 0;
                while (__hip_atomic_load(bepoch, __ATOMIC_RELAXED, __HIP_MEMORY_SCOPE_AGENT) <= t) {
                    __builtin_amdgcn_s_sleep(4);
                    if (++spins > 20000000) break;   // bail out instead of hanging
                }
            }
        }
        __syncthreads();
    }
}

// ---------- fp32 tail GEMM: C = act(A @ Wm + bias), tile 64x64 ----------
template <int ACT>
__global__ __launch_bounds__(256) void gemm64(
    const float* __restrict__ A, const float* __restrict__ Wm,
    const float* __restrict__ bias, float* __restrict__ out,
    int M, int N, int K)
{
    __shared__ float Asf[32][65];
    __shared__ float Bsf[32][65];
    const int c0 = blockIdx.x * 64;
    const int r0 = blockIdx.y * 64;
    const int tid = (int)threadIdx.x;
    const int tx = tid & 15, ty = tid >> 4;

    float acc[4][4];
    #pragma unroll
    for (int r = 0; r < 4; ++r) { acc[r][0]=0.f; acc[r][1]=0.f; acc[r][2]=0.f; acc[r][3]=0.f; }

    for (int k0 = 0; k0 < K; k0 += 32) {
        #pragma unroll
        for (int i = 0; i < 8; ++i) {
            int e = tid + 256 * i;
            int row = e >> 5, kk = e & 31;
            Asf[kk][row] = A[(size_t)(r0 + row) * K + k0 + kk];
        }
        #pragma unroll
        for (int i = 0; i < 8; ++i) {
            int e = tid + 256 * i;
            int kk = e >> 6, cl = e & 63;
            Bsf[kk][cl] = Wm[(size_t)(k0 + kk) * N + c0 + cl];
        }
        __syncthreads();
        #pragma unroll
        for (int kk = 0; kk < 32; ++kk) {
            float b0 = Bsf[kk][tx*4], b1 = Bsf[kk][tx*4+1], b2 = Bsf[kk][tx*4+2], b3 = Bsf[kk][tx*4+3];
            #pragma unroll
            for (int r = 0; r < 4; ++r) {
                float a = Asf[kk][ty*4 + r];
                acc[r][0] = fmaf(a, b0, acc[r][0]);
                acc[r][1] = fmaf(a, b1, acc[r][1]);
                acc[r][2] = fmaf(a, b2, acc[r][2]);
                acc[r][3] = fmaf(a, b3, acc[r][3]);
            }
        }
        __syncthreads();
    }
    #pragma unroll
    for (int r = 0; r < 4; ++r) {
        int gr = r0 + ty * 4 + r;
        #pragma unroll
        for (int j = 0; j < 4; ++j) {
            int gc = c0 + tx * 4 + j;
            float v = acc[r][j] + bias[gc];
            if (ACT) v = fmaxf(v, 0.f);
            out[(size_t)gr * N + gc] = v;
        }
    }
}

extern "C" void kernel_launch(void* const* d_in, const int* in_sizes, int n_in,
                              void* d_out, int out_size, void* d_ws, size_t ws_size,
                              hipStream_t stream)
{
    const float* X  = (const float*)d_in[0];
    const float* Wl = (const float*)d_in[1];
    const float* bl = (const float*)d_in[2];
    const float* Wd = (const float*)d_in[3];
    const float* bd = (const float*)d_in[4];
    const float* Wp = (const float*)d_in[5];
    const float* bp = (const float*)d_in[6];
    float* out = (float*)d_out;

    // ws layout
    char* p = (char*)d_ws;
    int* bar      = (int*)p; p += 4096;                              // 8 groups x 256 B
    u32* cells    = (u32*)p; p += NGRP * GWG * 16 * 4;               // 16 KB probe cells
    float* hf32   = (float*)p; p += (size_t)BATCH * NCELL * 4;       // 2 MB
    float* dense  = (float*)p; p += (size_t)BATCH * DENSE_N * 4;     // 8 MB
    u16* Wthi = (u16*)p; p += (size_t)ZC * KP * 2;                   // 2.23 MB
    u16* Wtlo = (u16*)p; p += (size_t)ZC * KP * 2;
    u32* H0   = (u32*)p; p += (size_t)BATCH * KP * 4;                // 2.23 MB
    u32* H1   = (u32*)p; p += (size_t)BATCH * KP * 4;

    (void)hipMemsetAsync(bar, 0, 4096 + NGRP * GWG * 16 * 4, stream);
    prep_w<<<(ZC * KP) / 256, 256, 0, stream>>>(Wl, Wthi, Wtlo);
    prep_h<<<(BATCH * KP) / 256, 256, 0, stream>>>(X, H0, H1);

    const int lds_bytes = 2 * 64 * KL * 2;   // 147456
    (void)hipFuncSetAttribute((const void*)lstm_persist,
                              hipFuncAttributeMaxDynamicSharedMemorySize, lds_bytes);
    lstm_persist<<<NWG, 256, lds_bytes, stream>>>(H0, H1, Wthi, Wtlo, bl, X, hf32, bar, cells);

    dim3 blk(256);
    gemm64<1><<<dim3(DENSE_N / 64, BATCH / 64), blk, 0, stream>>>(hf32, Wd, bd, dense, BATCH, DENSE_N, NCELL);
    gemm64<0><<<dim3(PRED_N / 64, BATCH / 64), blk, 0, stream>>>(dense, Wp, bp, out, BATCH, PRED_N, DENSE_N);
}

// Round 10
// 9507.594 us; speedup vs baseline: 1.0649x; 1.0649x over previous
//
#include <hip/hip_runtime.h>

#define BATCH 1024
#define SEQ 512
#define NFEAT 24
#define NCELL 512
#define ZC 2048      // 4*NCELL
#define KP 544       // reordered K: [h(512) | x(24) | pad(8)]
#define NCH 17       // K chunks of 32
#define KL 576       // LDS k-stride in u16 (XOR-swizzled in 16B units)
#define DENSE_N 2048
#define PRED_N 576
#define NWG 256
#define NGRP 8       // row groups == XCDs
#define GWG 32       // WGs per group == CUs per XCD

typedef unsigned short u16;
typedef unsigned int u32;
typedef unsigned long long u64;
typedef unsigned short u16x8 __attribute__((ext_vector_type(8)));
typedef short s16x8 __attribute__((ext_vector_type(8)));
typedef u32 u32x4 __attribute__((ext_vector_type(4)));
typedef float f32x4 __attribute__((ext_vector_type(4)));

__device__ __forceinline__ float sigm(float x) { return 1.f / (1.f + __expf(-x)); }
__device__ __forceinline__ float ftanh(float x) {
    float t = __expf(-2.f * fabsf(x));
    float r = (1.f - t) / (1.f + t);
    return copysignf(r, x);
}
__device__ __forceinline__ u16 f2b(float v) {           // f32 -> bf16 RTNE
    unsigned int x = __float_as_uint(v);
    unsigned int r = (x + 0x7fffu + ((x >> 16) & 1u)) >> 16;
    return (u16)r;
}
__device__ __forceinline__ float b2f(u16 u) { return __uint_as_float(((unsigned int)u) << 16); }

// Fragment-major H layout. u64 index: (((rb*4+wv)*NCH + ch)*8 + m*4 + i)*64 + lane.
__device__ __forceinline__ u32 hword(int row, int k) {
    int rb = row >> 7, wv = (row >> 5) & 3, m = (row >> 4) & 1, rl = row & 15;
    int ch = k >> 5, sub = (k & 31) >> 3, i = (k & 7) >> 1, w = k & 1;
    u32 q = (u32)(((rb * 4 + wv) * NCH + ch) * 8 + m * 4 + i) * 64u + (u32)(rl + (sub << 4));
    return q * 2u + (u32)w;
}

// unpack 8 packed cells (lo16=hi-plane bf16, hi16=lo-plane bf16) into two s16x8
__device__ __forceinline__ void unpack16(const u32x4 a, const u32x4 b, s16x8* hi, s16x8* lo) {
    u32* h = (u32*)hi; u32* l = (u32*)lo;
    h[0] = __builtin_amdgcn_perm(a[1], a[0], 0x05040100u);
    h[1] = __builtin_amdgcn_perm(a[3], a[2], 0x05040100u);
    h[2] = __builtin_amdgcn_perm(b[1], b[0], 0x05040100u);
    h[3] = __builtin_amdgcn_perm(b[3], b[2], 0x05040100u);
    l[0] = __builtin_amdgcn_perm(a[1], a[0], 0x07060302u);
    l[1] = __builtin_amdgcn_perm(a[3], a[2], 0x07060302u);
    l[2] = __builtin_amdgcn_perm(b[1], b[0], 0x07060302u);
    l[3] = __builtin_amdgcn_perm(b[3], b[2], 0x07060302u);
}

// ---------- prep: W -> transposed, K-reordered, split hi/lo ----------
__global__ __launch_bounds__(256) void prep_w(const float* __restrict__ W,
                                              u16* __restrict__ Whi, u16* __restrict__ Wlo) {
    int o = blockIdx.x * 256 + threadIdx.x;            // over ZC*KP
    if (o >= ZC * KP) return;
    int n = o / KP, k = o % KP;
    float v = 0.f;
    if (k < NCELL)              v = W[(size_t)(NFEAT + k) * ZC + n];   // h rows
    else if (k < NCELL + NFEAT) v = W[(size_t)(k - NCELL) * ZC + n];   // x rows
    u16 hi = f2b(v);
    u16 lo = f2b(v - b2f(hi));
    Whi[o] = hi; Wlo[o] = lo;
}

// ---------- prep: H0 = [h=0 | x_0 | pad=0], H1 = 0 (fragment-major packed u32) ----------
__global__ __launch_bounds__(256) void prep_h(const float* __restrict__ X,
                                              u32* __restrict__ H0, u32* __restrict__ H1) {
    int o = blockIdx.x * 256 + threadIdx.x;            // over BATCH*KP
    if (o >= BATCH * KP) return;
    int row = o / KP, k = o % KP;
    u32 pk = 0;
    if (k >= NCELL && k < NCELL + NFEAT) {
        float v = X[(size_t)row * (SEQ * NFEAT) + (k - NCELL)];  // t = 0
        u16 hi = f2b(v), lo = f2b(v - b2f(hi));
        pk = (u32)hi | ((u32)lo << 16);
    }
    u32 w = hword(row, k);
    H0[w] = pk;
    H1[w] = 0;
}

// ---------- persistent LSTM: XCD-pure groups via HW_REG_XCC_ID ----------
// rb = this WG's XCD id; nb = arrival slot within the XCD (0..31).
// All H traffic stays inside the XCD L2: plain write-back stores + sc0 loads.
// No cache-maintenance instructions anywhere in the step loop.
__global__ __launch_bounds__(256, 1) void lstm_persist(
    u32* __restrict__ H0, u32* __restrict__ H1,
    const u16* __restrict__ Wthi, const u16* __restrict__ Wtlo,  // [ZC][KP]
    const float* __restrict__ bias,                              // [ZC]
    const float* __restrict__ X,                                 // [BATCH][SEQ][NFEAT]
    float* __restrict__ hf32,                                    // [BATCH][NCELL]
    int* __restrict__ bar)                                       // barrier + slot counters
{
    extern __shared__ u16 Ws[];   // [2 planes][64 cols][KL], XOR-swizzled
    __shared__ int s_rb, s_nb;

    const int tid = (int)threadIdx.x;
    const int lane = tid & 63, wv = tid >> 6;

    // ---- self-assignment: rb = XCC_ID, nb = per-XCD slot ----
    if (tid == 0) {
        u32 xcc;
        asm volatile("s_getreg_b32 %0, hwreg(HW_REG_XCC_ID)" : "=s"(xcc));
        xcc &= 7u;
        int slot = __hip_atomic_fetch_add(&bar[512 + (int)xcc], 1,
                                          __ATOMIC_RELAXED, __HIP_MEMORY_SCOPE_AGENT);
        s_rb = (int)xcc;
        s_nb = slot & 31;
    }
    __syncthreads();
    const int rb = s_rb, nb = s_nb;
    const int r0 = rb * 128;
    int* __restrict__ bcnt   = bar + rb * 64;
    int* __restrict__ bepoch = bar + rb * 64 + 32;

    // ---- load W slice into LDS once (swizzled) ----
    #pragma unroll
    for (int p = 0; p < 2; ++p) {
        const u16* Wp = p ? Wtlo : Wthi;
        for (int e = tid; e < 64 * (KP / 8); e += 256) {
            int col = e / (KP / 8), k8 = (e % (KP / 8)) * 8;
            int zc = (col >> 4) * NCELL + nb * 16 + (col & 15);
            int so = k8 ^ ((col & 7) << 3);
            *(u16x8*)&Ws[(p * 64 + col) * KL + so] = *(const u16x8*)&Wp[(size_t)zc * KP + k8];
        }
    }
    __syncthreads();

    const int cell = nb * 16 + (lane & 15);
    const float bi = bias[cell], bj = bias[NCELL + cell];
    const float bf_ = bias[2 * NCELL + cell], bo = bias[3 * NCELL + cell];

    const int akof = (lane >> 4) * 8;                 // k sub-offset for B frags (u16)
    const u32 wbase = (u32)((rb * 4 + wv) * NCH) * 512u + (u32)lane;

    // epilogue store constants
    const int cellsub = ((nb & 1) << 1) + ((lane & 15) >> 3);
    const int celli = (lane & 7) >> 1;
    const int cellw = lane & 1;
    const u32 ebase = (u32)((rb * 4 + wv) * NCH + (nb >> 1)) * 512u;

    float ct[2][4] = {};   // persistent cell state in registers
    int dead = 0;          // tid0-only: barrier bailout flag

    for (int t = 0; t < SEQ; ++t) {
        const u64* Hq = (const u64*)((t & 1) ? H1 : H0);
        u32*       Np = (t & 1) ? H0 : H1;

        f32x4 acc[2][4] = {};   // [m][gate]
        u64 fr[3][8];           // A triple buffer: [buf][m*4+i]

#define ALOADF(f, ch) do { \
        _Pragma("unroll") \
        for (int m_ = 0; m_ < 2; ++m_) \
            _Pragma("unroll") \
            for (int i_ = 0; i_ < 4; ++i_) { \
                const u64* ap_ = &Hq[wbase + (u32)(ch) * 512u + (u32)m_ * 256u + (u32)i_ * 64u]; \
                asm volatile("global_load_dwordx2 %0, %1, off sc0" \
                             : "=v"(f[m_ * 4 + i_]) : "v"(ap_)); \
            } } while (0)
#define WAITV(n) do { asm volatile("s_waitcnt vmcnt(" #n ")" ::: "memory"); \
                      __builtin_amdgcn_sched_barrier(0); } while (0)
#define WSOFF(cb, off) ((cb) * KL + (((off)) ^ (((cb) & 7) << 3)))
#define CCOMP(f, ch) do { \
        s16x8 ah0, al0, ah1, al1; \
        unpack16(*(const u32x4*)&f[0], *(const u32x4*)&f[2], &ah0, &al0); \
        unpack16(*(const u32x4*)&f[4], *(const u32x4*)&f[6], &ah1, &al1); \
        s16x8 bh[4], bl[4]; \
        _Pragma("unroll") \
        for (int n = 0; n < 4; ++n) { \
            bh[n] = *(const s16x8*)&Ws[WSOFF(n * 16 + (lane & 15), (ch) * 32 + akof)]; \
            bl[n] = *(const s16x8*)&Ws[WSOFF(64 + n * 16 + (lane & 15), (ch) * 32 + akof)]; \
        } \
        _Pragma("unroll") \
        for (int n = 0; n < 4; ++n) { \
            acc[0][n] = __builtin_amdgcn_mfma_f32_16x16x32_bf16(ah0, bh[n], acc[0][n], 0, 0, 0); \
            acc[0][n] = __builtin_amdgcn_mfma_f32_16x16x32_bf16(ah0, bl[n], acc[0][n], 0, 0, 0); \
            acc[0][n] = __builtin_amdgcn_mfma_f32_16x16x32_bf16(al0, bh[n], acc[0][n], 0, 0, 0); \
            acc[1][n] = __builtin_amdgcn_mfma_f32_16x16x32_bf16(ah1, bh[n], acc[1][n], 0, 0, 0); \
            acc[1][n] = __builtin_amdgcn_mfma_f32_16x16x32_bf16(ah1, bl[n], acc[1][n], 0, 0, 0); \
            acc[1][n] = __builtin_amdgcn_mfma_f32_16x16x32_bf16(al1, bh[n], acc[1][n], 0, 0, 0); \
        } } while (0)

        ALOADF(fr[0], 0); ALOADF(fr[1], 1);
        #pragma unroll
        for (int ch = 0; ch < NCH; ++ch) {
            if (ch + 2 < NCH)      { ALOADF(fr[(ch + 2) % 3], ch + 2); WAITV(16); }
            else if (ch + 1 < NCH) { WAITV(8); }
            else                   { WAITV(0); }
            CCOMP(fr[ch % 3], ch);
        }
#undef ALOADF
#undef CCOMP

        // Fused gate epilogue; c in registers. TF gate order: i, j, f, o.
        // Plain write-back stores: data stays in this XCD's L2.
        #pragma unroll
        for (int m = 0; m < 2; ++m) {
            #pragma unroll
            for (int r = 0; r < 4; ++r) {
                int row = r0 + wv * 32 + m * 16 + (lane >> 4) * 4 + r;
                float zi = acc[m][0][r] + bi;
                float zj = acc[m][1][r] + bj;
                float zf = acc[m][2][r] + bf_;
                float zo = acc[m][3][r] + bo;
                float cn = ct[m][r] * sigm(zf + 1.0f) + sigm(zi) * ftanh(zj);
                ct[m][r] = cn;
                float h = ftanh(cn) * sigm(zo);
                u16 hh = f2b(h);
                u16 hl = f2b(h - b2f(hh));
                int lp = ((lane >> 4) << 2) + r + (cellsub << 4);
                u32 q = ebase + (u32)(m * 256 + celli * 64 + lp);
                Np[q * 2u + (u32)cellw] = (u32)hh | ((u32)hl << 16);
                if (t == SEQ - 1) hf32[(size_t)row * NCELL + cell] = h;
            }
        }
        // Stage next step's x-slice into the next A plane (fragment-major).
        if (t + 1 < SEQ && nb < NFEAT && tid < 128) {
            int row = r0 + tid;
            float v = X[(size_t)row * (SEQ * NFEAT) + (t + 1) * NFEAT + nb];
            u16 vh = f2b(v), vl = f2b(v - b2f(vh));
            int wv2 = tid >> 5, m2 = (tid >> 4) & 1;
            int lp = (tid & 15) + ((nb >> 3) << 4);
            u32 q = (u32)((rb * 4 + wv2) * NCH + 16) * 512u
                  + (u32)(m2 * 256 + ((nb & 7) >> 1) * 64 + lp);
            Np[q * 2u + (u32)(nb & 1)] = (u32)vh | ((u32)vl << 16);
        }

        // ---- row-group barrier: pure L3 atomics; stores already in shared L2 ----
        __syncthreads();   // vmcnt drained: plain stores visible in XCD L2
        if (tid == 0 && !dead) {
            int n = __hip_atomic_fetch_add(bcnt, 1, __ATOMIC_RELAXED, __HIP_MEMORY_SCOPE_AGENT);
            if (n == GWG - 1) {
                __hip_atomic_store(bcnt, 0, __ATOMIC_RELAXED, __HIP_MEMORY_SCOPE_AGENT);
                __hip_atomic_store(bepoch, t + 1, __ATOMIC_RELAXED, __HIP_MEMORY_SCOPE_AGENT);
            } else {
                int spins = 0;
                while (__hip_atomic_load(bepoch, __ATOMIC_RELAXED, __HIP_MEMORY_SCOPE_AGENT) <= t) {
                    __builtin_amdgcn_s_sleep(4);
                    if (++spins > 2000000) { dead = 1; break; }   // fail fast, visibly
                }
            }
        }
        __syncthreads();
    }
}

// ---------- fp32 tail GEMM: C = act(A @ Wm + bias), tile 64x64 ----------
template <int ACT>
__global__ __launch_bounds__(256) void gemm64(
    const float* __restrict__ A, const float* __restrict__ Wm,
    const float* __restrict__ bias, float* __restrict__ out,
    int M, int N, int K)
{
    __shared__ float Asf[32][65];
    __shared__ float Bsf[32][65];
    const int c0 = blockIdx.x * 64;
    const int r0 = blockIdx.y * 64;
    const int tid = (int)threadIdx.x;
    const int tx = tid & 15, ty = tid >> 4;

    float acc[4][4];
    #pragma unroll
    for (int r = 0; r < 4; ++r) { acc[r][0]=0.f; acc[r][1]=0.f; acc[r][2]=0.f; acc[r][3]=0.f; }

    for (int k0 = 0; k0 < K; k0 += 32) {
        #pragma unroll
        for (int i = 0; i < 8; ++i) {
            int e = tid + 256 * i;
            int row = e >> 5, kk = e & 31;
            Asf[kk][row] = A[(size_t)(r0 + row) * K + k0 + kk];
        }
        #pragma unroll
        for (int i = 0; i < 8; ++i) {
            int e = tid + 256 * i;
            int kk = e >> 6, cl = e & 63;
            Bsf[kk][cl] = Wm[(size_t)(k0 + kk) * N + c0 + cl];
        }
        __syncthreads();
        #pragma unroll
        for (int kk = 0; kk < 32; ++kk) {
            float b0 = Bsf[kk][tx*4], b1 = Bsf[kk][tx*4+1], b2 = Bsf[kk][tx*4+2], b3 = Bsf[kk][tx*4+3];
            #pragma unroll
            for (int r = 0; r < 4; ++r) {
                float a = Asf[kk][ty*4 + r];
                acc[r][0] = fmaf(a, b0, acc[r][0]);
                acc[r][1] = fmaf(a, b1, acc[r][1]);
                acc[r][2] = fmaf(a, b2, acc[r][2]);
                acc[r][3] = fmaf(a, b3, acc[r][3]);
            }
        }
        __syncthreads();
    }
    #pragma unroll
    for (int r = 0; r < 4; ++r) {
        int gr = r0 + ty * 4 + r;
        #pragma unroll
        for (int j = 0; j < 4; ++j) {
            int gc = c0 + tx * 4 + j;
            float v = acc[r][j] + bias[gc];
            if (ACT) v = fmaxf(v, 0.f);
            out[(size_t)gr * N + gc] = v;
        }
    }
}

extern "C" void kernel_launch(void* const* d_in, const int* in_sizes, int n_in,
                              void* d_out, int out_size, void* d_ws, size_t ws_size,
                              hipStream_t stream)
{
    const float* X  = (const float*)d_in[0];
    const float* Wl = (const float*)d_in[1];
    const float* bl = (const float*)d_in[2];
    const float* Wd = (const float*)d_in[3];
    const float* bd = (const float*)d_in[4];
    const float* Wp = (const float*)d_in[5];
    const float* bp = (const float*)d_in[6];
    float* out = (float*)d_out;

    // ws layout
    char* p = (char*)d_ws;
    int* bar      = (int*)p; p += 4096;                              // barriers + slot counters
    float* hf32   = (float*)p; p += (size_t)BATCH * NCELL * 4;       // 2 MB
    float* dense  = (float*)p; p += (size_t)BATCH * DENSE_N * 4;     // 8 MB
    u16* Wthi = (u16*)p; p += (size_t)ZC * KP * 2;                   // 2.23 MB
    u16* Wtlo = (u16*)p; p += (size_t)ZC * KP * 2;
    u32* H0   = (u32*)p; p += (size_t)BATCH * KP * 4;                // 2.23 MB
    u32* H1   = (u32*)p; p += (size_t)BATCH * KP * 4;

    (void)hipMemsetAsync(bar, 0, 4096, stream);
    prep_w<<<(ZC * KP) / 256, 256, 0, stream>>>(Wl, Wthi, Wtlo);
    prep_h<<<(BATCH * KP) / 256, 256, 0, stream>>>(X, H0, H1);

    const int lds_bytes = 2 * 64 * KL * 2;   // 147456
    (void)hipFuncSetAttribute((const void*)lstm_persist,
                              hipFuncAttributeMaxDynamicSharedMemorySize, lds_bytes);
    lstm_persist<<<NWG, 256, lds_bytes, stream>>>(H0, H1, Wthi, Wtlo, bl, X, hf32, bar);

    dim3 blk(256);
    gemm64<1><<<dim3(DENSE_N / 64, BATCH / 64), blk, 0, stream>>>(hf32, Wd, bd, dense, BATCH, DENSE_N, NCELL);
    gemm64<0><<<dim3(PRED_N / 64, BATCH / 64), blk, 0, stream>>>(dense, Wp, bp, out, BATCH, PRED_N, DENSE_N);
}

// Round 11
// 9335.323 us; speedup vs baseline: 1.0845x; 1.0185x over previous
//
#include <hip/hip_runtime.h>

#define BATCH 1024
#define SEQ 512
#define NFEAT 24
#define NCELL 512
#define ZC 2048      // 4*NCELL
#define KP 544       // reordered K: [h(512) | x(24) | pad(8)]
#define NCH 17       // K chunks of 32
#define KL 576       // LDS k-stride in u16 (XOR-swizzled in 16B units)
#define DENSE_N 2048
#define PRED_N 576
#define NWG 256
#define NGRP 8       // row groups == XCDs
#define GWG 32       // WGs per group == CUs per XCD

typedef unsigned short u16;
typedef unsigned int u32;
typedef unsigned long long u64;
typedef unsigned short u16x8 __attribute__((ext_vector_type(8)));
typedef short s16x8 __attribute__((ext_vector_type(8)));
typedef u32 u32x4 __attribute__((ext_vector_type(4)));
typedef float f32x4 __attribute__((ext_vector_type(4)));

__device__ __forceinline__ float sigm(float x) { return 1.f / (1.f + __expf(-x)); }
__device__ __forceinline__ float ftanh(float x) {
    float t = __expf(-2.f * fabsf(x));
    float r = (1.f - t) / (1.f + t);
    return copysignf(r, x);
}
__device__ __forceinline__ u16 f2b(float v) {           // f32 -> bf16 RTNE
    unsigned int x = __float_as_uint(v);
    unsigned int r = (x + 0x7fffu + ((x >> 16) & 1u)) >> 16;
    return (u16)r;
}
__device__ __forceinline__ float b2f(u16 u) { return __uint_as_float(((unsigned int)u) << 16); }

// Fragment-major H layout. u64 index: (((rb*4+wv)*NCH + ch)*8 + m*4 + i)*64 + lane.
__device__ __forceinline__ u32 hword(int row, int k) {
    int rb = row >> 7, wv = (row >> 5) & 3, m = (row >> 4) & 1, rl = row & 15;
    int ch = k >> 5, sub = (k & 31) >> 3, i = (k & 7) >> 1, w = k & 1;
    u32 q = (u32)(((rb * 4 + wv) * NCH + ch) * 8 + m * 4 + i) * 64u + (u32)(rl + (sub << 4));
    return q * 2u + (u32)w;
}

// unpack 8 packed cells (lo16=hi-plane bf16, hi16=lo-plane bf16) into two s16x8
__device__ __forceinline__ void unpack16(const u32x4 a, const u32x4 b, s16x8* hi, s16x8* lo) {
    u32* h = (u32*)hi; u32* l = (u32*)lo;
    h[0] = __builtin_amdgcn_perm(a[1], a[0], 0x05040100u);
    h[1] = __builtin_amdgcn_perm(a[3], a[2], 0x05040100u);
    h[2] = __builtin_amdgcn_perm(b[1], b[0], 0x05040100u);
    h[3] = __builtin_amdgcn_perm(b[3], b[2], 0x05040100u);
    l[0] = __builtin_amdgcn_perm(a[1], a[0], 0x07060302u);
    l[1] = __builtin_amdgcn_perm(a[3], a[2], 0x07060302u);
    l[2] = __builtin_amdgcn_perm(b[1], b[0], 0x07060302u);
    l[3] = __builtin_amdgcn_perm(b[3], b[2], 0x07060302u);
}

// ---------- prep: W -> transposed, K-reordered, split hi/lo ----------
__global__ __launch_bounds__(256) void prep_w(const float* __restrict__ W,
                                              u16* __restrict__ Whi, u16* __restrict__ Wlo) {
    int o = blockIdx.x * 256 + threadIdx.x;            // over ZC*KP
    if (o >= ZC * KP) return;
    int n = o / KP, k = o % KP;
    float v = 0.f;
    if (k < NCELL)              v = W[(size_t)(NFEAT + k) * ZC + n];   // h rows
    else if (k < NCELL + NFEAT) v = W[(size_t)(k - NCELL) * ZC + n];   // x rows
    u16 hi = f2b(v);
    u16 lo = f2b(v - b2f(hi));
    Whi[o] = hi; Wlo[o] = lo;
}

// ---------- prep: H0 = [h=0 | x_0 | pad=0], H1 = 0 (fragment-major packed u32) ----------
__global__ __launch_bounds__(256) void prep_h(const float* __restrict__ X,
                                              u32* __restrict__ H0, u32* __restrict__ H1) {
    int o = blockIdx.x * 256 + threadIdx.x;            // over BATCH*KP
    if (o >= BATCH * KP) return;
    int row = o / KP, k = o % KP;
    u32 pk = 0;
    if (k >= NCELL && k < NCELL + NFEAT) {
        float v = X[(size_t)row * (SEQ * NFEAT) + (k - NCELL)];  // t = 0
        u16 hi = f2b(v), lo = f2b(v - b2f(hi));
        pk = (u32)hi | ((u32)lo << 16);
    }
    u32 w = hword(row, k);
    H0[w] = pk;
    H1[w] = 0;
}

// ---------- persistent LSTM: XCD-pure groups via HW_REG_XCC_ID ----------
// rb = this WG's XCD id; nb = arrival slot within the XCD (0..31).
// H traffic stays inside the XCD L2: plain write-back stores + plain loads.
// L1 staleness handled by ONE buffer_inv (vector-L1 invalidate) per step.
__global__ __launch_bounds__(256, 1) void lstm_persist(
    u32* __restrict__ H0, u32* __restrict__ H1,
    const u16* __restrict__ Wthi, const u16* __restrict__ Wtlo,  // [ZC][KP]
    const float* __restrict__ bias,                              // [ZC]
    const float* __restrict__ X,                                 // [BATCH][SEQ][NFEAT]
    float* __restrict__ hf32,                                    // [BATCH][NCELL]
    int* __restrict__ bar)                                       // barrier + slot counters
{
    extern __shared__ u16 Ws[];   // [2 planes][64 cols][KL], XOR-swizzled
    __shared__ int s_rb, s_nb;

    const int tid = (int)threadIdx.x;
    const int lane = tid & 63, wv = tid >> 6;

    // ---- self-assignment: rb = XCC_ID, nb = per-XCD slot ----
    if (tid == 0) {
        u32 xcc;
        asm volatile("s_getreg_b32 %0, hwreg(HW_REG_XCC_ID)" : "=s"(xcc));
        xcc &= 7u;
        int slot = __hip_atomic_fetch_add(&bar[512 + (int)xcc], 1,
                                          __ATOMIC_RELAXED, __HIP_MEMORY_SCOPE_AGENT);
        s_rb = (int)xcc;
        s_nb = slot & 31;
    }
    __syncthreads();
    const int rb = s_rb, nb = s_nb;
    const int r0 = rb * 128;
    int* __restrict__ bcnt   = bar + rb * 64;
    int* __restrict__ bepoch = bar + rb * 64 + 32;

    // ---- load W slice into LDS once (swizzled) ----
    #pragma unroll
    for (int p = 0; p < 2; ++p) {
        const u16* Wp = p ? Wtlo : Wthi;
        for (int e = tid; e < 64 * (KP / 8); e += 256) {
            int col = e / (KP / 8), k8 = (e % (KP / 8)) * 8;
            int zc = (col >> 4) * NCELL + nb * 16 + (col & 15);
            int so = k8 ^ ((col & 7) << 3);
            *(u16x8*)&Ws[(p * 64 + col) * KL + so] = *(const u16x8*)&Wp[(size_t)zc * KP + k8];
        }
    }
    __syncthreads();

    const int cell = nb * 16 + (lane & 15);
    const float bi = bias[cell], bj = bias[NCELL + cell];
    const float bf_ = bias[2 * NCELL + cell], bo = bias[3 * NCELL + cell];

    const int akof = (lane >> 4) * 8;                 // k sub-offset for B frags (u16)
    const u32 wbase = (u32)((rb * 4 + wv) * NCH) * 512u + (u32)lane;

    // epilogue store constants
    const int cellsub = ((nb & 1) << 1) + ((lane & 15) >> 3);
    const int celli = (lane & 7) >> 1;
    const int cellw = lane & 1;
    const u32 ebase = (u32)((rb * 4 + wv) * NCH + (nb >> 1)) * 512u;

    float ct[2][4] = {};   // persistent cell state in registers
    int dead = 0;          // tid0-only: barrier bailout flag

    for (int t = 0; t < SEQ; ++t) {
        // Invalidate this CU's vector L1 once: the H ping-pong buffer re-read
        // this step was rewritten by OTHER CUs (same XCD L2) last step.
        asm volatile("buffer_inv" ::: "memory");

        const u64* __restrict__ Hq = (const u64*)((t & 1) ? H1 : H0);
        u32*       __restrict__ Np = (t & 1) ? H0 : H1;

        f32x4 acc[2][4] = {};   // [m][gate]
        u64 fr[3][8];           // A triple buffer: [buf][m*4+i]

#define ALOADP(f, ch) do { \
        _Pragma("unroll") \
        for (int m_ = 0; m_ < 2; ++m_) \
            _Pragma("unroll") \
            for (int i_ = 0; i_ < 4; ++i_) \
                f[m_ * 4 + i_] = Hq[wbase + (u32)(ch) * 512u + (u32)m_ * 256u + (u32)i_ * 64u]; \
        } while (0)
#define WSOFF(cb, off) ((cb) * KL + (((off)) ^ (((cb) & 7) << 3)))
#define CCOMP(f, ch) do { \
        s16x8 ah0, al0, ah1, al1; \
        unpack16(*(const u32x4*)&f[0], *(const u32x4*)&f[2], &ah0, &al0); \
        unpack16(*(const u32x4*)&f[4], *(const u32x4*)&f[6], &ah1, &al1); \
        s16x8 bh[4], bl[4]; \
        _Pragma("unroll") \
        for (int n = 0; n < 4; ++n) { \
            bh[n] = *(const s16x8*)&Ws[WSOFF(n * 16 + (lane & 15), (ch) * 32 + akof)]; \
            bl[n] = *(const s16x8*)&Ws[WSOFF(64 + n * 16 + (lane & 15), (ch) * 32 + akof)]; \
        } \
        _Pragma("unroll") \
        for (int n = 0; n < 4; ++n) { \
            acc[0][n] = __builtin_amdgcn_mfma_f32_16x16x32_bf16(ah0, bh[n], acc[0][n], 0, 0, 0); \
            acc[0][n] = __builtin_amdgcn_mfma_f32_16x16x32_bf16(ah0, bl[n], acc[0][n], 0, 0, 0); \
            acc[0][n] = __builtin_amdgcn_mfma_f32_16x16x32_bf16(al0, bh[n], acc[0][n], 0, 0, 0); \
            acc[1][n] = __builtin_amdgcn_mfma_f32_16x16x32_bf16(ah1, bh[n], acc[1][n], 0, 0, 0); \
            acc[1][n] = __builtin_amdgcn_mfma_f32_16x16x32_bf16(ah1, bl[n], acc[1][n], 0, 0, 0); \
            acc[1][n] = __builtin_amdgcn_mfma_f32_16x16x32_bf16(al1, bh[n], acc[1][n], 0, 0, 0); \
        } } while (0)

        ALOADP(fr[0], 0); ALOADP(fr[1], 1);
        #pragma unroll
        for (int ch = 0; ch < NCH; ++ch) {
            if (ch + 2 < NCH) ALOADP(fr[(ch + 2) % 3], ch + 2);
            CCOMP(fr[ch % 3], ch);
        }
#undef ALOADP
#undef CCOMP

        // Fused gate epilogue; c in registers. TF gate order: i, j, f, o.
        // Plain write-back stores: data stays in this XCD's L2.
        #pragma unroll
        for (int m = 0; m < 2; ++m) {
            #pragma unroll
            for (int r = 0; r < 4; ++r) {
                int row = r0 + wv * 32 + m * 16 + (lane >> 4) * 4 + r;
                float zi = acc[m][0][r] + bi;
                float zj = acc[m][1][r] + bj;
                float zf = acc[m][2][r] + bf_;
                float zo = acc[m][3][r] + bo;
                float cn = ct[m][r] * sigm(zf + 1.0f) + sigm(zi) * ftanh(zj);
                ct[m][r] = cn;
                float h = ftanh(cn) * sigm(zo);
                u16 hh = f2b(h);
                u16 hl = f2b(h - b2f(hh));
                int lp = ((lane >> 4) << 2) + r + (cellsub << 4);
                u32 q = ebase + (u32)(m * 256 + celli * 64 + lp);
                Np[q * 2u + (u32)cellw] = (u32)hh | ((u32)hl << 16);
                if (t == SEQ - 1) hf32[(size_t)row * NCELL + cell] = h;
            }
        }
        // Stage next step's x-slice into the next A plane (fragment-major).
        if (t + 1 < SEQ && nb < NFEAT && tid < 128) {
            int row = r0 + tid;
            float v = X[(size_t)row * (SEQ * NFEAT) + (t + 1) * NFEAT + nb];
            u16 vh = f2b(v), vl = f2b(v - b2f(vh));
            int wv2 = tid >> 5, m2 = (tid >> 4) & 1;
            int lp = (tid & 15) + ((nb >> 3) << 4);
            u32 q = (u32)((rb * 4 + wv2) * NCH + 16) * 512u
                  + (u32)(m2 * 256 + ((nb & 7) >> 1) * 64 + lp);
            Np[q * 2u + (u32)(nb & 1)] = (u32)vh | ((u32)vl << 16);
        }

        // ---- row-group barrier: pure L3 atomics; stores already in shared L2 ----
        __syncthreads();   // vmcnt drained: plain stores visible in XCD L2
        if (tid == 0 && !dead) {
            int n = __hip_atomic_fetch_add(bcnt, 1, __ATOMIC_RELAXED, __HIP_MEMORY_SCOPE_AGENT);
            if (n == GWG - 1) {
                __hip_atomic_store(bcnt, 0, __ATOMIC_RELAXED, __HIP_MEMORY_SCOPE_AGENT);
                __hip_atomic_store(bepoch, t + 1, __ATOMIC_RELAXED, __HIP_MEMORY_SCOPE_AGENT);
            } else {
                int spins = 0;
                while (__hip_atomic_load(bepoch, __ATOMIC_RELAXED, __HIP_MEMORY_SCOPE_AGENT) <= t) {
                    __builtin_amdgcn_s_sleep(4);
                    if (++spins > 2000000) { dead = 1; break; }   // fail fast, visibly
                }
            }
        }
        __syncthreads();
    }
}

// ---------- fp32 tail GEMM: C = act(A @ Wm + bias), tile 64x64 ----------
template <int ACT>
__global__ __launch_bounds__(256) void gemm64(
    const float* __restrict__ A, const float* __restrict__ Wm,
    const float* __restrict__ bias, float* __restrict__ out,
    int M, int N, int K)
{
    __shared__ float Asf[32][65];
    __shared__ float Bsf[32][65];
    const int c0 = blockIdx.x * 64;
    const int r0 = blockIdx.y * 64;
    const int tid = (int)threadIdx.x;
    const int tx = tid & 15, ty = tid >> 4;

    float acc[4][4];
    #pragma unroll
    for (int r = 0; r < 4; ++r) { acc[r][0]=0.f; acc[r][1]=0.f; acc[r][2]=0.f; acc[r][3]=0.f; }

    for (int k0 = 0; k0 < K; k0 += 32) {
        #pragma unroll
        for (int i = 0; i < 8; ++i) {
            int e = tid + 256 * i;
            int row = e >> 5, kk = e & 31;
            Asf[kk][row] = A[(size_t)(r0 + row) * K + k0 + kk];
        }
        #pragma unroll
        for (int i = 0; i < 8; ++i) {
            int e = tid + 256 * i;
            int kk = e >> 6, cl = e & 63;
            Bsf[kk][cl] = Wm[(size_t)(k0 + kk) * N + c0 + cl];
        }
        __syncthreads();
        #pragma unroll
        for (int kk = 0; kk < 32; ++kk) {
            float b0 = Bsf[kk][tx*4], b1 = Bsf[kk][tx*4+1], b2 = Bsf[kk][tx*4+2], b3 = Bsf[kk][tx*4+3];
            #pragma unroll
            for (int r = 0; r < 4; ++r) {
                float a = Asf[kk][ty*4 + r];
                acc[r][0] = fmaf(a, b0, acc[r][0]);
                acc[r][1] = fmaf(a, b1, acc[r][1]);
                acc[r][2] = fmaf(a, b2, acc[r][2]);
                acc[r][3] = fmaf(a, b3, acc[r][3]);
            }
        }
        __syncthreads();
    }
    #pragma unroll
    for (int r = 0; r < 4; ++r) {
        int gr = r0 + ty * 4 + r;
        #pragma unroll
        for (int j = 0; j < 4; ++j) {
            int gc = c0 + tx * 4 + j;
            float v = acc[r][j] + bias[gc];
            if (ACT) v = fmaxf(v, 0.f);
            out[(size_t)gr * N + gc] = v;
        }
    }
}

extern "C" void kernel_launch(void* const* d_in, const int* in_sizes, int n_in,
                              void* d_out, int out_size, void* d_ws, size_t ws_size,
                              hipStream_t stream)
{
    const float* X  = (const float*)d_in[0];
    const float* Wl = (const float*)d_in[1];
    const float* bl = (const float*)d_in[2];
    const float* Wd = (const float*)d_in[3];
    const float* bd = (const float*)d_in[4];
    const float* Wp = (const float*)d_in[5];
    const float* bp = (const float*)d_in[6];
    float* out = (float*)d_out;

    // ws layout
    char* p = (char*)d_ws;
    int* bar      = (int*)p; p += 4096;                              // barriers + slot counters
    float* hf32   = (float*)p; p += (size_t)BATCH * NCELL * 4;       // 2 MB
    float* dense  = (float*)p; p += (size_t)BATCH * DENSE_N * 4;     // 8 MB
    u16* Wthi = (u16*)p; p += (size_t)ZC * KP * 2;                   // 2.23 MB
    u16* Wtlo = (u16*)p; p += (size_t)ZC * KP * 2;
    u32* H0   = (u32*)p; p += (size_t)BATCH * KP * 4;                // 2.23 MB
    u32* H1   = (u32*)p; p += (size_t)BATCH * KP * 4;

    (void)hipMemsetAsync(bar, 0, 4096, stream);
    prep_w<<<(ZC * KP) / 256, 256, 0, stream>>>(Wl, Wthi, Wtlo);
    prep_h<<<(BATCH * KP) / 256, 256, 0, stream>>>(X, H0, H1);

    const int lds_bytes = 2 * 64 * KL * 2;   // 147456
    (void)hipFuncSetAttribute((const void*)lstm_persist,
                              hipFuncAttributeMaxDynamicSharedMemorySize, lds_bytes);
    lstm_persist<<<NWG, 256, lds_bytes, stream>>>(H0, H1, Wthi, Wtlo, bl, X, hf32, bar);

    dim3 blk(256);
    gemm64<1><<<dim3(DENSE_N / 64, BATCH / 64), blk, 0, stream>>>(hf32, Wd, bd, dense, BATCH, DENSE_N, NCELL);
    gemm64<0><<<dim3(PRED_N / 64, BATCH / 64), blk, 0, stream>>>(dense, Wp, bp, out, BATCH, PRED_N, DENSE_N);
}

// Round 12
// 4524.398 us; speedup vs baseline: 2.2378x; 2.0633x over previous
//
#include <hip/hip_runtime.h>

#define BATCH 1024
#define SEQ 512
#define NFEAT 24
#define NCELL 512
#define ZC 2048      // 4*NCELL
#define KP 544       // reordered K: [h(512) | x(24) | pad(8)]
#define NCH 17       // K chunks of 32
#define KL 576       // LDS k-stride in u16 (XOR-swizzled in 16B units)
#define DENSE_N 2048
#define PRED_N 576
#define NWG 256
#define NGRP 8       // row groups (128 rows each)
#define GWG 32       // WGs per group
#define PFD 4        // A-prefetch depth in chunks (covers ~L3 latency)
#define NBUF 5       // PFD + 1

typedef unsigned short u16;
typedef unsigned int u32;
typedef unsigned long long u64;
typedef unsigned short u16x8 __attribute__((ext_vector_type(8)));
typedef short s16x8 __attribute__((ext_vector_type(8)));
typedef u32 u32x4 __attribute__((ext_vector_type(4)));
typedef float f32x4 __attribute__((ext_vector_type(4)));

__device__ __forceinline__ float sigm(float x) { return 1.f / (1.f + __expf(-x)); }
__device__ __forceinline__ float ftanh(float x) {
    float t = __expf(-2.f * fabsf(x));
    float r = (1.f - t) / (1.f + t);
    return copysignf(r, x);
}
__device__ __forceinline__ u16 f2b(float v) {           // f32 -> bf16 RTNE
    unsigned int x = __float_as_uint(v);
    unsigned int r = (x + 0x7fffu + ((x >> 16) & 1u)) >> 16;
    return (u16)r;
}
__device__ __forceinline__ float b2f(u16 u) { return __uint_as_float(((unsigned int)u) << 16); }

// Fragment-major H layout. u64 index: (((rb*4+wv)*NCH + ch)*8 + m*4 + i)*64 + lane.
__device__ __forceinline__ u32 hword(int row, int k) {
    int rb = row >> 7, wv = (row >> 5) & 3, m = (row >> 4) & 1, rl = row & 15;
    int ch = k >> 5, sub = (k & 31) >> 3, i = (k & 7) >> 1, w = k & 1;
    u32 q = (u32)(((rb * 4 + wv) * NCH + ch) * 8 + m * 4 + i) * 64u + (u32)(rl + (sub << 4));
    return q * 2u + (u32)w;
}

// unpack 8 packed cells (lo16=hi-plane bf16, hi16=lo-plane bf16) into two s16x8
__device__ __forceinline__ void unpack16(const u32x4 a, const u32x4 b, s16x8* hi, s16x8* lo) {
    u32* h = (u32*)hi; u32* l = (u32*)lo;
    h[0] = __builtin_amdgcn_perm(a[1], a[0], 0x05040100u);
    h[1] = __builtin_amdgcn_perm(a[3], a[2], 0x05040100u);
    h[2] = __builtin_amdgcn_perm(b[1], b[0], 0x05040100u);
    h[3] = __builtin_amdgcn_perm(b[3], b[2], 0x05040100u);
    l[0] = __builtin_amdgcn_perm(a[1], a[0], 0x07060302u);
    l[1] = __builtin_amdgcn_perm(a[3], a[2], 0x07060302u);
    l[2] = __builtin_amdgcn_perm(b[1], b[0], 0x07060302u);
    l[3] = __builtin_amdgcn_perm(b[3], b[2], 0x07060302u);
}

// ---------- prep: W -> transposed, K-reordered, split hi/lo ----------
__global__ __launch_bounds__(256) void prep_w(const float* __restrict__ W,
                                              u16* __restrict__ Whi, u16* __restrict__ Wlo) {
    int o = blockIdx.x * 256 + threadIdx.x;            // over ZC*KP
    if (o >= ZC * KP) return;
    int n = o / KP, k = o % KP;
    float v = 0.f;
    if (k < NCELL)              v = W[(size_t)(NFEAT + k) * ZC + n];   // h rows
    else if (k < NCELL + NFEAT) v = W[(size_t)(k - NCELL) * ZC + n];   // x rows
    u16 hi = f2b(v);
    u16 lo = f2b(v - b2f(hi));
    Whi[o] = hi; Wlo[o] = lo;
}

// ---------- prep: H0 = [h=0 | x_0 | pad=0], H1 = 0 (fragment-major packed u32) ----------
__global__ __launch_bounds__(256) void prep_h(const float* __restrict__ X,
                                              u32* __restrict__ H0, u32* __restrict__ H1) {
    int o = blockIdx.x * 256 + threadIdx.x;            // over BATCH*KP
    if (o >= BATCH * KP) return;
    int row = o / KP, k = o % KP;
    u32 pk = 0;
    if (k >= NCELL && k < NCELL + NFEAT) {
        float v = X[(size_t)row * (SEQ * NFEAT) + (k - NCELL)];  // t = 0
        u16 hi = f2b(v), lo = f2b(v - b2f(hi));
        pk = (u32)hi | ((u32)lo << 16);
    }
    u32 w = hword(row, k);
    H0[w] = pk;
    H1[w] = 0;
}

// ---------- persistent LSTM: round-8 protocol (read-through loads,
// write-through stores, no cache maintenance), prefetch depth 4 ----------
__global__ __launch_bounds__(256, 1) void lstm_persist(
    u32* __restrict__ H0, u32* __restrict__ H1,
    const u16* __restrict__ Wthi, const u16* __restrict__ Wtlo,  // [ZC][KP]
    const float* __restrict__ bias,                              // [ZC]
    const float* __restrict__ X,                                 // [BATCH][SEQ][NFEAT]
    float* __restrict__ hf32,                                    // [BATCH][NCELL]
    int* __restrict__ bar)                                       // 8 x 64 ints
{
    extern __shared__ u16 Ws[];   // [2 planes][64 cols][KL], XOR-swizzled

    const int tid = (int)threadIdx.x;
    const int bid = (int)blockIdx.x;
    const int rb = bid & 7, nb = bid >> 3;
    const int r0 = rb * 128;
    const int lane = tid & 63, wv = tid >> 6;
    int* __restrict__ bcnt   = bar + rb * 64;
    int* __restrict__ bepoch = bar + rb * 64 + 32;

    // ---- load W slice into LDS once (swizzled) ----
    #pragma unroll
    for (int p = 0; p < 2; ++p) {
        const u16* Wp = p ? Wtlo : Wthi;
        for (int e = tid; e < 64 * (KP / 8); e += 256) {
            int col = e / (KP / 8), k8 = (e % (KP / 8)) * 8;
            int zc = (col >> 4) * NCELL + nb * 16 + (col & 15);
            int so = k8 ^ ((col & 7) << 3);
            *(u16x8*)&Ws[(p * 64 + col) * KL + so] = *(const u16x8*)&Wp[(size_t)zc * KP + k8];
        }
    }
    __syncthreads();

    const int cell = nb * 16 + (lane & 15);
    const float bi = bias[cell], bj = bias[NCELL + cell];
    const float bf_ = bias[2 * NCELL + cell], bo = bias[3 * NCELL + cell];

    const int akof = (lane >> 4) * 8;                 // k sub-offset for B frags (u16)
    const u32 wbase = (u32)((rb * 4 + wv) * NCH) * 512u + (u32)lane;

    // epilogue store constants
    const int cellsub = ((nb & 1) << 1) + ((lane & 15) >> 3);
    const int celli = (lane & 7) >> 1;
    const int cellw = lane & 1;
    const u32 ebase = (u32)((rb * 4 + wv) * NCH + (nb >> 1)) * 512u;

    float ct[2][4] = {};   // persistent cell state in registers

    for (int t = 0; t < SEQ; ++t) {
        const u64* Hq = (const u64*)((t & 1) ? H1 : H0);
        u32*       Np = (t & 1) ? H0 : H1;

        f32x4 acc[2][4] = {};   // [m][gate]
        u64 fr[NBUF][8];        // A prefetch ring: [buf][m*4+i]

#define ALOADS(f, ch) do { \
        _Pragma("unroll") \
        for (int m_ = 0; m_ < 2; ++m_) \
            _Pragma("unroll") \
            for (int i_ = 0; i_ < 4; ++i_) \
                f[m_ * 4 + i_] = __hip_atomic_load( \
                    &Hq[wbase + (u32)(ch) * 512u + (u32)m_ * 256u + (u32)i_ * 64u], \
                    __ATOMIC_RELAXED, __HIP_MEMORY_SCOPE_AGENT); } while (0)
#define WSOFF(cb, off) ((cb) * KL + (((off)) ^ (((cb) & 7) << 3)))
#define CCOMP(f, ch) do { \
        s16x8 ah0, al0, ah1, al1; \
        unpack16(*(const u32x4*)&f[0], *(const u32x4*)&f[2], &ah0, &al0); \
        unpack16(*(const u32x4*)&f[4], *(const u32x4*)&f[6], &ah1, &al1); \
        s16x8 bh[4], bl[4]; \
        _Pragma("unroll") \
        for (int n = 0; n < 4; ++n) { \
            bh[n] = *(const s16x8*)&Ws[WSOFF(n * 16 + (lane & 15), (ch) * 32 + akof)]; \
            bl[n] = *(const s16x8*)&Ws[WSOFF(64 + n * 16 + (lane & 15), (ch) * 32 + akof)]; \
        } \
        _Pragma("unroll") \
        for (int n = 0; n < 4; ++n) { \
            acc[0][n] = __builtin_amdgcn_mfma_f32_16x16x32_bf16(ah0, bh[n], acc[0][n], 0, 0, 0); \
            acc[0][n] = __builtin_amdgcn_mfma_f32_16x16x32_bf16(ah0, bl[n], acc[0][n], 0, 0, 0); \
            acc[0][n] = __builtin_amdgcn_mfma_f32_16x16x32_bf16(al0, bh[n], acc[0][n], 0, 0, 0); \
            acc[1][n] = __builtin_amdgcn_mfma_f32_16x16x32_bf16(ah1, bh[n], acc[1][n], 0, 0, 0); \
            acc[1][n] = __builtin_amdgcn_mfma_f32_16x16x32_bf16(ah1, bl[n], acc[1][n], 0, 0, 0); \
            acc[1][n] = __builtin_amdgcn_mfma_f32_16x16x32_bf16(al1, bh[n], acc[1][n], 0, 0, 0); \
        } } while (0)

        ALOADS(fr[0], 0); ALOADS(fr[1], 1); ALOADS(fr[2], 2); ALOADS(fr[3], 3);
        #pragma unroll
        for (int ch = 0; ch < NCH; ++ch) {
            if (ch + PFD < NCH) ALOADS(fr[(ch + PFD) % NBUF], ch + PFD);
            CCOMP(fr[ch % NBUF], ch);
        }
#undef ALOADS
#undef CCOMP

        // Fused gate epilogue; c in registers. TF gate order: i, j, f, o.
        #pragma unroll
        for (int m = 0; m < 2; ++m) {
            #pragma unroll
            for (int r = 0; r < 4; ++r) {
                int row = r0 + wv * 32 + m * 16 + (lane >> 4) * 4 + r;
                float zi = acc[m][0][r] + bi;
                float zj = acc[m][1][r] + bj;
                float zf = acc[m][2][r] + bf_;
                float zo = acc[m][3][r] + bo;
                float cn = ct[m][r] * sigm(zf + 1.0f) + sigm(zi) * ftanh(zj);
                ct[m][r] = cn;
                float h = ftanh(cn) * sigm(zo);
                u16 hh = f2b(h);
                u16 hl = f2b(h - b2f(hh));
                u32 pk = (u32)hh | ((u32)hl << 16);
                int lp = ((lane >> 4) << 2) + r + (cellsub << 4);
                u32 q = ebase + (u32)(m * 256 + celli * 64 + lp);
                __hip_atomic_store(&Np[q * 2u + (u32)cellw], pk,
                                   __ATOMIC_RELAXED, __HIP_MEMORY_SCOPE_AGENT);
                if (t == SEQ - 1) hf32[(size_t)row * NCELL + cell] = h;
            }
        }
        // Stage next step's x-slice into the next A plane (fragment-major).
        if (t + 1 < SEQ && nb < NFEAT && tid < 128) {
            int row = r0 + tid;
            float v = X[(size_t)row * (SEQ * NFEAT) + (t + 1) * NFEAT + nb];
            u16 vh = f2b(v), vl = f2b(v - b2f(vh));
            u32 pk = (u32)vh | ((u32)vl << 16);
            int wv2 = tid >> 5, m2 = (tid >> 4) & 1;
            int lp = (tid & 15) + ((nb >> 3) << 4);
            u32 q = (u32)((rb * 4 + wv2) * NCH + 16) * 512u
                  + (u32)(m2 * 256 + ((nb & 7) >> 1) * 64 + lp);
            __hip_atomic_store(&Np[q * 2u + (u32)(nb & 1)], pk,
                               __ATOMIC_RELAXED, __HIP_MEMORY_SCOPE_AGENT);
        }

        // ---- row-group barrier: pure atomics, NO cache maintenance ----
        __syncthreads();   // vmcnt drained: write-through stores visible at L3
        if (tid == 0) {
            int n = __hip_atomic_fetch_add(bcnt, 1, __ATOMIC_RELAXED, __HIP_MEMORY_SCOPE_AGENT);
            if (n == GWG - 1) {
                __hip_atomic_store(bcnt, 0, __ATOMIC_RELAXED, __HIP_MEMORY_SCOPE_AGENT);
                __hip_atomic_store(bepoch, t + 1, __ATOMIC_RELEASE, __HIP_MEMORY_SCOPE_AGENT);
            } else {
                int spins = 0;
                while (__hip_atomic_load(bepoch, __ATOMIC_RELAXED, __HIP_MEMORY_SCOPE_AGENT) <= t) {
                    __builtin_amdgcn_s_sleep(4);
                    if (++spins > 20000000) break;   // bail out instead of hanging
                }
            }
        }
        __syncthreads();
        // no fence: next step's H reads are read-through atomics (always coherent)
    }
}

// ---------- fp32 tail GEMM: C = act(A @ Wm + bias), tile 64x64 ----------
template <int ACT>
__global__ __launch_bounds__(256) void gemm64(
    const float* __restrict__ A, const float* __restrict__ Wm,
    const float* __restrict__ bias, float* __restrict__ out,
    int M, int N, int K)
{
    __shared__ float Asf[32][65];
    __shared__ float Bsf[32][65];
    const int c0 = blockIdx.x * 64;
    const int r0 = blockIdx.y * 64;
    const int tid = (int)threadIdx.x;
    const int tx = tid & 15, ty = tid >> 4;

    float acc[4][4];
    #pragma unroll
    for (int r = 0; r < 4; ++r) { acc[r][0]=0.f; acc[r][1]=0.f; acc[r][2]=0.f; acc[r][3]=0.f; }

    for (int k0 = 0; k0 < K; k0 += 32) {
        #pragma unroll
        for (int i = 0; i < 8; ++i) {
            int e = tid + 256 * i;
            int row = e >> 5, kk = e & 31;
            Asf[kk][row] = A[(size_t)(r0 + row) * K + k0 + kk];
        }
        #pragma unroll
        for (int i = 0; i < 8; ++i) {
            int e = tid + 256 * i;
            int kk = e >> 6, cl = e & 63;
            Bsf[kk][cl] = Wm[(size_t)(k0 + kk) * N + c0 + cl];
        }
        __syncthreads();
        #pragma unroll
        for (int kk = 0; kk < 32; ++kk) {
            float b0 = Bsf[kk][tx*4], b1 = Bsf[kk][tx*4+1], b2 = Bsf[kk][tx*4+2], b3 = Bsf[kk][tx*4+3];
            #pragma unroll
            for (int r = 0; r < 4; ++r) {
                float a = Asf[kk][ty*4 + r];
                acc[r][0] = fmaf(a, b0, acc[r][0]);
                acc[r][1] = fmaf(a, b1, acc[r][1]);
                acc[r][2] = fmaf(a, b2, acc[r][2]);
                acc[r][3] = fmaf(a, b3, acc[r][3]);
            }
        }
        __syncthreads();
    }
    #pragma unroll
    for (int r = 0; r < 4; ++r) {
        int gr = r0 + ty * 4 + r;
        #pragma unroll
        for (int j = 0; j < 4; ++j) {
            int gc = c0 + tx * 4 + j;
            float v = acc[r][j] + bias[gc];
            if (ACT) v = fmaxf(v, 0.f);
            out[(size_t)gr * N + gc] = v;
        }
    }
}

extern "C" void kernel_launch(void* const* d_in, const int* in_sizes, int n_in,
                              void* d_out, int out_size, void* d_ws, size_t ws_size,
                              hipStream_t stream)
{
    const float* X  = (const float*)d_in[0];
    const float* Wl = (const float*)d_in[1];
    const float* bl = (const float*)d_in[2];
    const float* Wd = (const float*)d_in[3];
    const float* bd = (const float*)d_in[4];
    const float* Wp = (const float*)d_in[5];
    const float* bp = (const float*)d_in[6];
    float* out = (float*)d_out;

    // ws layout
    char* p = (char*)d_ws;
    int* bar      = (int*)p; p += 4096;                              // 8 groups x 256 B
    float* hf32   = (float*)p; p += (size_t)BATCH * NCELL * 4;       // 2 MB
    float* dense  = (float*)p; p += (size_t)BATCH * DENSE_N * 4;     // 8 MB
    u16* Wthi = (u16*)p; p += (size_t)ZC * KP * 2;                   // 2.23 MB
    u16* Wtlo = (u16*)p; p += (size_t)ZC * KP * 2;
    u32* H0   = (u32*)p; p += (size_t)BATCH * KP * 4;                // 2.23 MB
    u32* H1   = (u32*)p; p += (size_t)BATCH * KP * 4;

    (void)hipMemsetAsync(bar, 0, 4096, stream);
    prep_w<<<(ZC * KP) / 256, 256, 0, stream>>>(Wl, Wthi, Wtlo);
    prep_h<<<(BATCH * KP) / 256, 256, 0, stream>>>(X, H0, H1);

    const int lds_bytes = 2 * 64 * KL * 2;   // 147456
    (void)hipFuncSetAttribute((const void*)lstm_persist,
                              hipFuncAttributeMaxDynamicSharedMemorySize, lds_bytes);
    lstm_persist<<<NWG, 256, lds_bytes, stream>>>(H0, H1, Wthi, Wtlo, bl, X, hf32, bar);

    dim3 blk(256);
    gemm64<1><<<dim3(DENSE_N / 64, BATCH / 64), blk, 0, stream>>>(hf32, Wd, bd, dense, BATCH, DENSE_N, NCELL);
    gemm64<0><<<dim3(PRED_N / 64, BATCH / 64), blk, 0, stream>>>(dense, Wp, bp, out, BATCH, PRED_N, DENSE_N);
}

// Round 13
// 3372.994 us; speedup vs baseline: 3.0017x; 1.3414x over previous
//
#include <hip/hip_runtime.h>
#include <hip/hip_fp16.h>

#define BATCH 1024
#define SEQ 512
#define NFEAT 24
#define NCELL 512
#define ZC 2048      // 4*NCELL
#define KP 544       // reordered K: [h(512) | x(24) | pad(8)]
#define NCH 17       // K chunks of 32
#define KL 576       // LDS k-stride in u16 (XOR-swizzled in 16B units)
#define DENSE_N 2048
#define PRED_N 576
#define NWG 256
#define NGRP 8       // row groups (128 rows each)
#define GWG 32       // WGs per group
#define PFD 4        // A-prefetch depth in chunks
#define NBUF 5       // PFD + 1

typedef unsigned short u16;
typedef unsigned int u32;
typedef unsigned long long u64;
typedef unsigned short u16x8 __attribute__((ext_vector_type(8)));
typedef _Float16 f16x8 __attribute__((ext_vector_type(8)));
typedef float f32x4 __attribute__((ext_vector_type(4)));

__device__ __forceinline__ float sigm(float x) { return 1.f / (1.f + __expf(-x)); }
__device__ __forceinline__ float ftanh(float x) {
    float t = __expf(-2.f * fabsf(x));
    float r = (1.f - t) / (1.f + t);
    return copysignf(r, x);
}
__device__ __forceinline__ u16 f2h(float v) {            // f32 -> f16 RTNE
    _Float16 h = (_Float16)v;
    return *(u16*)&h;
}
// write-through 2B store (agent-visible at vmcnt drain), exact cache bits
__device__ __forceinline__ void st16(u16* p, u32 v) {
    asm volatile("global_store_short %0, %1, off sc0 sc1" :: "v"(p), "v"(v) : "memory");
}

// Fragment-major fp16 H layout. frag_id = ((rb*4+wv)*NCH + ch)*2 + m; 1 KB/frag.
// u16 index for element (row, k):
__device__ __forceinline__ u32 hword16(int row, int k) {
    int rb = row >> 7, wv = (row >> 5) & 3, m = (row >> 4) & 1;
    int ch = k >> 5;
    int lane = (row & 15) | (((k >> 3) & 3) << 4);
    return (u32)((((rb * 4 + wv) * NCH + ch) * 2 + m) * 512 + lane * 8 + (k & 7));
}

// ---------- prep: W -> transposed, K-reordered, fp16 ----------
__global__ __launch_bounds__(256) void prep_w(const float* __restrict__ W,
                                              u16* __restrict__ Wt) {
    int o = blockIdx.x * 256 + threadIdx.x;            // over ZC*KP
    if (o >= ZC * KP) return;
    int n = o / KP, k = o % KP;
    float v = 0.f;
    if (k < NCELL)              v = W[(size_t)(NFEAT + k) * ZC + n];   // h rows
    else if (k < NCELL + NFEAT) v = W[(size_t)(k - NCELL) * ZC + n];   // x rows
    Wt[o] = f2h(v);
}

// ---------- prep: H0 = [h=0 | x_0 | pad=0], H1 = 0 (fragment-major fp16) ----------
__global__ __launch_bounds__(256) void prep_h(const float* __restrict__ X,
                                              u16* __restrict__ H0, u16* __restrict__ H1) {
    int o = blockIdx.x * 256 + threadIdx.x;            // over BATCH*KP
    if (o >= BATCH * KP) return;
    int row = o / KP, k = o % KP;
    u16 b = 0;
    if (k >= NCELL && k < NCELL + NFEAT)
        b = f2h(X[(size_t)row * (SEQ * NFEAT) + (k - NCELL)]);   // t = 0
    u32 w = hword16(row, k);
    H0[w] = b;
    H1[w] = 0;
}

// ---------- persistent LSTM: fp16 single-pass MFMA, r12 protocol ----------
// (read-through A loads, write-through H stores, pure-atomic group barrier)
__global__ __launch_bounds__(256, 1) void lstm_persist(
    u16* __restrict__ H0, u16* __restrict__ H1,
    const u16* __restrict__ Wt,                                  // [ZC][KP] fp16
    const float* __restrict__ bias,                              // [ZC]
    const float* __restrict__ X,                                 // [BATCH][SEQ][NFEAT]
    float* __restrict__ hf32,                                    // [BATCH][NCELL]
    int* __restrict__ bar)                                       // 8 x 64 ints
{
    extern __shared__ u16 Ws[];   // [64 cols][KL] fp16, XOR-swizzled

    const int tid = (int)threadIdx.x;
    const int bid = (int)blockIdx.x;
    const int rb = bid & 7, nb = bid >> 3;
    const int r0 = rb * 128;
    const int lane = tid & 63, wv = tid >> 6;
    int* __restrict__ bcnt   = bar + rb * 64;
    int* __restrict__ bepoch = bar + rb * 64 + 32;

    // ---- load W slice into LDS once (swizzled) ----
    for (int e = tid; e < 64 * (KP / 8); e += 256) {
        int col = e / (KP / 8), k8 = (e % (KP / 8)) * 8;
        int zc = (col >> 4) * NCELL + nb * 16 + (col & 15);
        int so = k8 ^ ((col & 7) << 3);
        *(u16x8*)&Ws[col * KL + so] = *(const u16x8*)&Wt[(size_t)zc * KP + k8];
    }
    __syncthreads();

    const int cell = nb * 16 + (lane & 15);
    const float bi = bias[cell], bj = bias[NCELL + cell];
    const float bf_ = bias[2 * NCELL + cell], bo = bias[3 * NCELL + cell];

    const int akof = (lane >> 4) * 8;                 // k sub-offset for B frags (u16)
    // A-load bases (u64 units): frag_id*128 + lane*2
    const u32 abase0 = (u32)(((rb * 4 + wv) * NCH) * 2 + 0) * 128u + (u32)lane * 2u;
    const u32 abase1 = abase0 + 128u;

    // epilogue store constants
    const int esub = (((nb & 1) * 2 + ((lane & 15) >> 3)) << 4);
    const u32 efrag = (u32)((rb * 4 + wv) * NCH + (nb >> 1)) * 2u;

    float ct[2][4] = {};   // persistent cell state in registers

    for (int t = 0; t < SEQ; ++t) {
        const u64* Hq = (const u64*)((t & 1) ? H1 : H0);
        u16*       Np = (t & 1) ? H0 : H1;

        f32x4 acc[2][4] = {};                      // [m][gate]
        __attribute__((aligned(16))) u64 fr[NBUF][4];  // A ring: [buf][m*2+half]

#define ALOADS(f, ch) do { \
        f[0] = __hip_atomic_load(&Hq[abase0 + (u32)(ch) * 256u],     __ATOMIC_RELAXED, __HIP_MEMORY_SCOPE_AGENT); \
        f[1] = __hip_atomic_load(&Hq[abase0 + (u32)(ch) * 256u + 1], __ATOMIC_RELAXED, __HIP_MEMORY_SCOPE_AGENT); \
        f[2] = __hip_atomic_load(&Hq[abase1 + (u32)(ch) * 256u],     __ATOMIC_RELAXED, __HIP_MEMORY_SCOPE_AGENT); \
        f[3] = __hip_atomic_load(&Hq[abase1 + (u32)(ch) * 256u + 1], __ATOMIC_RELAXED, __HIP_MEMORY_SCOPE_AGENT); \
        } while (0)
#define WSOFF(cb, off) ((cb) * KL + (((off)) ^ (((cb) & 7) << 3)))
#define CCOMP(f, ch) do { \
        f16x8 a0 = *(const f16x8*)&f[0]; \
        f16x8 a1 = *(const f16x8*)&f[2]; \
        _Pragma("unroll") \
        for (int n = 0; n < 4; ++n) { \
            f16x8 bn = *(const f16x8*)&Ws[WSOFF(n * 16 + (lane & 15), (ch) * 32 + akof)]; \
            acc[0][n] = __builtin_amdgcn_mfma_f32_16x16x32_f16(a0, bn, acc[0][n], 0, 0, 0); \
            acc[1][n] = __builtin_amdgcn_mfma_f32_16x16x32_f16(a1, bn, acc[1][n], 0, 0, 0); \
        } } while (0)

        ALOADS(fr[0], 0); ALOADS(fr[1], 1); ALOADS(fr[2], 2); ALOADS(fr[3], 3);
        #pragma unroll
        for (int ch = 0; ch < NCH; ++ch) {
            if (ch + PFD < NCH) ALOADS(fr[(ch + PFD) % NBUF], ch + PFD);
            CCOMP(fr[ch % NBUF], ch);
        }
#undef ALOADS
#undef CCOMP

        // Fused gate epilogue; c in registers. TF gate order: i, j, f, o.
        #pragma unroll
        for (int m = 0; m < 2; ++m) {
            #pragma unroll
            for (int r = 0; r < 4; ++r) {
                int row = r0 + wv * 32 + m * 16 + (lane >> 4) * 4 + r;
                float zi = acc[m][0][r] + bi;
                float zj = acc[m][1][r] + bj;
                float zf = acc[m][2][r] + bf_;
                float zo = acc[m][3][r] + bo;
                float cn = ct[m][r] * sigm(zf + 1.0f) + sigm(zi) * ftanh(zj);
                ct[m][r] = cn;
                float h = ftanh(cn) * sigm(zo);
                int elane = ((lane >> 4) * 4 + r) | esub;
                u32 idx = (efrag + (u32)m) * 512u + (u32)(elane * 8 + (lane & 7));
                st16(&Np[idx], (u32)f2h(h));
                if (t == SEQ - 1) hf32[(size_t)row * NCELL + cell] = h;
            }
        }
        // Stage next step's x-slice into the next A plane (fragment-major).
        if (t + 1 < SEQ && nb < NFEAT && tid < 128) {
            int row = r0 + tid;
            float v = X[(size_t)row * (SEQ * NFEAT) + (t + 1) * NFEAT + nb];
            int wv2 = tid >> 5, m2 = (tid >> 4) & 1;
            int elane2 = (tid & 15) | ((nb >> 3) << 4);
            u32 idx = (u32)(((rb * 4 + wv2) * NCH + 16) * 2 + m2) * 512u
                    + (u32)(elane2 * 8 + (nb & 7));
            st16(&Np[idx], (u32)f2h(v));
        }

        // ---- row-group barrier: pure atomics, NO cache maintenance ----
        __syncthreads();   // vmcnt drained: write-through stores visible at L3
        if (tid == 0) {
            int n = __hip_atomic_fetch_add(bcnt, 1, __ATOMIC_RELAXED, __HIP_MEMORY_SCOPE_AGENT);
            if (n == GWG - 1) {
                __hip_atomic_store(bcnt, 0, __ATOMIC_RELAXED, __HIP_MEMORY_SCOPE_AGENT);
                __hip_atomic_store(bepoch, t + 1, __ATOMIC_RELEASE, __HIP_MEMORY_SCOPE_AGENT);
            } else {
                int spins = 0;
                while (__hip_atomic_load(bepoch, __ATOMIC_RELAXED, __HIP_MEMORY_SCOPE_AGENT) <= t) {
                    __builtin_amdgcn_s_sleep(4);
                    if (++spins > 20000000) break;   // bail out instead of hanging
                }
            }
        }
        __syncthreads();
        // no fence: next step's H reads are read-through atomics (always coherent)
    }
}

// ---------- fp32 tail GEMM: C = act(A @ Wm + bias), tile 64x64 ----------
template <int ACT>
__global__ __launch_bounds__(256) void gemm64(
    const float* __restrict__ A, const float* __restrict__ Wm,
    const float* __restrict__ bias, float* __restrict__ out,
    int M, int N, int K)
{
    __shared__ float Asf[32][65];
    __shared__ float Bsf[32][65];
    const int c0 = blockIdx.x * 64;
    const int r0 = blockIdx.y * 64;
    const int tid = (int)threadIdx.x;
    const int tx = tid & 15, ty = tid >> 4;

    float acc[4][4];
    #pragma unroll
    for (int r = 0; r < 4; ++r) { acc[r][0]=0.f; acc[r][1]=0.f; acc[r][2]=0.f; acc[r][3]=0.f; }

    for (int k0 = 0; k0 < K; k0 += 32) {
        #pragma unroll
        for (int i = 0; i < 8; ++i) {
            int e = tid + 256 * i;
            int row = e >> 5, kk = e & 31;
            Asf[kk][row] = A[(size_t)(r0 + row) * K + k0 + kk];
        }
        #pragma unroll
        for (int i = 0; i < 8; ++i) {
            int e = tid + 256 * i;
            int kk = e >> 6, cl = e & 63;
            Bsf[kk][cl] = Wm[(size_t)(k0 + kk) * N + c0 + cl];
        }
        __syncthreads();
        #pragma unroll
        for (int kk = 0; kk < 32; ++kk) {
            float b0 = Bsf[kk][tx*4], b1 = Bsf[kk][tx*4+1], b2 = Bsf[kk][tx*4+2], b3 = Bsf[kk][tx*4+3];
            #pragma unroll
            for (int r = 0; r < 4; ++r) {
                float a = Asf[kk][ty*4 + r];
                acc[r][0] = fmaf(a, b0, acc[r][0]);
                acc[r][1] = fmaf(a, b1, acc[r][1]);
                acc[r][2] = fmaf(a, b2, acc[r][2]);
                acc[r][3] = fmaf(a, b3, acc[r][3]);
            }
        }
        __syncthreads();
    }
    #pragma unroll
    for (int r = 0; r < 4; ++r) {
        int gr = r0 + ty * 4 + r;
        #pragma unroll
        for (int j = 0; j < 4; ++j) {
            int gc = c0 + tx * 4 + j;
            float v = acc[r][j] + bias[gc];
            if (ACT) v = fmaxf(v, 0.f);
            out[(size_t)gr * N + gc] = v;
        }
    }
}

extern "C" void kernel_launch(void* const* d_in, const int* in_sizes, int n_in,
                              void* d_out, int out_size, void* d_ws, size_t ws_size,
                              hipStream_t stream)
{
    const float* X  = (const float*)d_in[0];
    const float* Wl = (const float*)d_in[1];
    const float* bl = (const float*)d_in[2];
    const float* Wd = (const float*)d_in[3];
    const float* bd = (const float*)d_in[4];
    const float* Wp = (const float*)d_in[5];
    const float* bp = (const float*)d_in[6];
    float* out = (float*)d_out;

    // ws layout
    char* p = (char*)d_ws;
    int* bar      = (int*)p; p += 4096;                              // 8 groups x 256 B
    float* hf32   = (float*)p; p += (size_t)BATCH * NCELL * 4;       // 2 MB
    float* dense  = (float*)p; p += (size_t)BATCH * DENSE_N * 4;     // 8 MB
    u16* Wt   = (u16*)p; p += (size_t)ZC * KP * 2;                   // 2.23 MB fp16
    u16* H0   = (u16*)p; p += (size_t)BATCH * KP * 2;                // 1.11 MB
    u16* H1   = (u16*)p; p += (size_t)BATCH * KP * 2;

    (void)hipMemsetAsync(bar, 0, 4096, stream);
    prep_w<<<(ZC * KP) / 256, 256, 0, stream>>>(Wl, Wt);
    prep_h<<<(BATCH * KP) / 256, 256, 0, stream>>>(X, H0, H1);

    const int lds_bytes = 64 * KL * 2;   // 73728
    (void)hipFuncSetAttribute((const void*)lstm_persist,
                              hipFuncAttributeMaxDynamicSharedMemorySize, lds_bytes);
    lstm_persist<<<NWG, 256, lds_bytes, stream>>>(H0, H1, Wt, bl, X, hf32, bar);

    dim3 blk(256);
    gemm64<1><<<dim3(DENSE_N / 64, BATCH / 64), blk, 0, stream>>>(hf32, Wd, bd, dense, BATCH, DENSE_N, NCELL);
    gemm64<0><<<dim3(PRED_N / 64, BATCH / 64), blk, 0, stream>>>(dense, Wp, bp, out, BATCH, PRED_N, DENSE_N);
}

// Round 14
// 3189.570 us; speedup vs baseline: 3.1743x; 1.0575x over previous
//
#include <hip/hip_runtime.h>
#include <hip/hip_fp16.h>

#define BATCH 1024
#define SEQ 512
#define NFEAT 24
#define NCELL 512
#define ZC 2048      // 4*NCELL
#define KP 544       // reordered K: [h(512) | x(24) | pad(8)]
#define NCH 17       // K chunks of 32
#define KL 576       // LDS k-stride in u16 (XOR-swizzled in 16B units)
#define DENSE_N 2048
#define PRED_N 576
#define NWG 256
#define NGRP 8       // row groups (128 rows each)
#define GWG 32       // WGs per group
#define PFD 4        // A-prefetch depth in chunks
#define NBUF 5       // PFD + 1

typedef unsigned short u16;
typedef unsigned int u32;
typedef unsigned long long u64;
typedef unsigned short u16x8 __attribute__((ext_vector_type(8)));
typedef _Float16 f16x8 __attribute__((ext_vector_type(8)));
typedef float f32x4 __attribute__((ext_vector_type(4)));

__device__ __forceinline__ float sigm(float x) { return 1.f / (1.f + __expf(-x)); }
__device__ __forceinline__ float ftanh(float x) {
    float t = __expf(-2.f * fabsf(x));
    float r = (1.f - t) / (1.f + t);
    return copysignf(r, x);
}
__device__ __forceinline__ u16 f2h(float v) {            // f32 -> f16 RTNE
    _Float16 h = (_Float16)v;
    return *(u16*)&h;
}
// write-through stores (agent-visible at vmcnt drain), exact cache bits
__device__ __forceinline__ void st16(u16* p, u32 v) {
    asm volatile("global_store_short %0, %1, off sc0 sc1" :: "v"(p), "v"(v) : "memory");
}
__device__ __forceinline__ void st128(u16* p, u16x8 v) {
    asm volatile("global_store_dwordx4 %0, %1, off sc0 sc1" :: "v"(p), "v"(v) : "memory");
}

// Fragment-major fp16 H layout. frag_id = ((rb*4+wv)*NCH + ch)*2 + m; 1 KB/frag.
// u16 index for element (row, k):
__device__ __forceinline__ u32 hword16(int row, int k) {
    int rb = row >> 7, wv = (row >> 5) & 3, m = (row >> 4) & 1;
    int ch = k >> 5;
    int lane = (row & 15) | (((k >> 3) & 3) << 4);
    return (u32)((((rb * 4 + wv) * NCH + ch) * 2 + m) * 512 + lane * 8 + (k & 7));
}

// ---------- prep: W -> transposed, K-reordered, fp16 ----------
__global__ __launch_bounds__(256) void prep_w(const float* __restrict__ W,
                                              u16* __restrict__ Wt) {
    int o = blockIdx.x * 256 + threadIdx.x;            // over ZC*KP
    if (o >= ZC * KP) return;
    int n = o / KP, k = o % KP;
    float v = 0.f;
    if (k < NCELL)              v = W[(size_t)(NFEAT + k) * ZC + n];   // h rows
    else if (k < NCELL + NFEAT) v = W[(size_t)(k - NCELL) * ZC + n];   // x rows
    Wt[o] = f2h(v);
}

// ---------- prep: H0 = [h=0 | x_0 | pad=0], H1 = 0 (fragment-major fp16) ----------
__global__ __launch_bounds__(256) void prep_h(const float* __restrict__ X,
                                              u16* __restrict__ H0, u16* __restrict__ H1) {
    int o = blockIdx.x * 256 + threadIdx.x;            // over BATCH*KP
    if (o >= BATCH * KP) return;
    int row = o / KP, k = o % KP;
    u16 b = 0;
    if (k >= NCELL && k < NCELL + NFEAT)
        b = f2h(X[(size_t)row * (SEQ * NFEAT) + (k - NCELL)]);   // t = 0
    u32 w = hword16(row, k);
    H0[w] = b;
    H1[w] = 0;
}

// ---------- persistent LSTM: fp16 single-pass MFMA, r13 protocol,
// LDS-staged coalesced H-stores, relaxed epoch ----------
__global__ __launch_bounds__(256, 1) void lstm_persist(
    u16* __restrict__ H0, u16* __restrict__ H1,
    const u16* __restrict__ Wt,                                  // [ZC][KP] fp16
    const float* __restrict__ bias,                              // [ZC]
    const float* __restrict__ X,                                 // [BATCH][SEQ][NFEAT]
    float* __restrict__ hf32,                                    // [BATCH][NCELL]
    int* __restrict__ bar)                                       // 8 x 64 ints
{
    extern __shared__ u16 Ws[];   // [64 cols][KL] fp16 swizzled | Hs: 4 x 512 u16

    const int tid = (int)threadIdx.x;
    const int bid = (int)blockIdx.x;
    const int rb = bid & 7, nb = bid >> 3;
    const int r0 = rb * 128;
    const int lane = tid & 63, wv = tid >> 6;
    u16* __restrict__ Hs = Ws + 64 * KL;      // per-wave 512-u16 staging tiles
    int* __restrict__ bcnt   = bar + rb * 64;
    int* __restrict__ bepoch = bar + rb * 64 + 32;

    // ---- load W slice into LDS once (swizzled) ----
    for (int e = tid; e < 64 * (KP / 8); e += 256) {
        int col = e / (KP / 8), k8 = (e % (KP / 8)) * 8;
        int zc = (col >> 4) * NCELL + nb * 16 + (col & 15);
        int so = k8 ^ ((col & 7) << 3);
        *(u16x8*)&Ws[col * KL + so] = *(const u16x8*)&Wt[(size_t)zc * KP + k8];
    }
    __syncthreads();

    const int cell = nb * 16 + (lane & 15);
    const float bi = bias[cell], bj = bias[NCELL + cell];
    const float bf_ = bias[2 * NCELL + cell], bo = bias[3 * NCELL + cell];

    const int akof = (lane >> 4) * 8;                 // k sub-offset for B frags (u16)
    // A-load bases (u64 units): frag_id*128 + lane*2
    const u32 abase0 = (u32)(((rb * 4 + wv) * NCH) * 2 + 0) * 128u + (u32)lane * 2u;
    const u32 abase1 = abase0 + 128u;

    // epilogue constants
    const int esub2 = (nb & 1) * 2;                    // k sub-block base within frag
    const u32 efrag = (u32)((rb * 4 + wv) * NCH + (nb >> 1)) * 2u;
    // one coalesced 16B store per thread: lanes 0-31 -> m=0 half-frag, 32-63 -> m=1
    const u32 esto = ((efrag + (u32)(lane >> 5)) << 9)            // frag base (u16)
                   + (u32)((esub2 * 16 + (lane & 31)) << 3);      // flane*8
    const int hsw = (wv << 9);                         // this wave's Hs tile

    float ct[2][4] = {};   // persistent cell state in registers

    for (int t = 0; t < SEQ; ++t) {
        const u64* Hq = (const u64*)((t & 1) ? H1 : H0);
        u16*       Np = (t & 1) ? H0 : H1;

        f32x4 acc[2][4] = {};                      // [m][gate]
        __attribute__((aligned(16))) u64 fr[NBUF][4];  // A ring: [buf][m*2+half]

#define ALOADS(f, ch) do { \
        f[0] = __hip_atomic_load(&Hq[abase0 + (u32)(ch) * 256u],     __ATOMIC_RELAXED, __HIP_MEMORY_SCOPE_AGENT); \
        f[1] = __hip_atomic_load(&Hq[abase0 + (u32)(ch) * 256u + 1], __ATOMIC_RELAXED, __HIP_MEMORY_SCOPE_AGENT); \
        f[2] = __hip_atomic_load(&Hq[abase1 + (u32)(ch) * 256u],     __ATOMIC_RELAXED, __HIP_MEMORY_SCOPE_AGENT); \
        f[3] = __hip_atomic_load(&Hq[abase1 + (u32)(ch) * 256u + 1], __ATOMIC_RELAXED, __HIP_MEMORY_SCOPE_AGENT); \
        } while (0)
#define WSOFF(cb, off) ((cb) * KL + (((off)) ^ (((cb) & 7) << 3)))
#define CCOMP(f, ch) do { \
        f16x8 a0 = *(const f16x8*)&f[0]; \
        f16x8 a1 = *(const f16x8*)&f[2]; \
        _Pragma("unroll") \
        for (int n = 0; n < 4; ++n) { \
            f16x8 bn = *(const f16x8*)&Ws[WSOFF(n * 16 + (lane & 15), (ch) * 32 + akof)]; \
            acc[0][n] = __builtin_amdgcn_mfma_f32_16x16x32_f16(a0, bn, acc[0][n], 0, 0, 0); \
            acc[1][n] = __builtin_amdgcn_mfma_f32_16x16x32_f16(a1, bn, acc[1][n], 0, 0, 0); \
        } } while (0)

        ALOADS(fr[0], 0); ALOADS(fr[1], 1); ALOADS(fr[2], 2); ALOADS(fr[3], 3);
        #pragma unroll
        for (int ch = 0; ch < NCH; ++ch) {
            if (ch + PFD < NCH) ALOADS(fr[(ch + PFD) % NBUF], ch + PFD);
            CCOMP(fr[ch % NBUF], ch);
        }
#undef ALOADS
#undef CCOMP

        // Fused gate epilogue; c in registers. TF gate order: i, j, f, o.
        // Stage h into wave-private LDS tile, then ONE coalesced 16B store.
        #pragma unroll
        for (int m = 0; m < 2; ++m) {
            #pragma unroll
            for (int r = 0; r < 4; ++r) {
                int row16 = (lane >> 4) * 4 + r;
                float zi = acc[m][0][r] + bi;
                float zj = acc[m][1][r] + bj;
                float zf = acc[m][2][r] + bf_;
                float zo = acc[m][3][r] + bo;
                float cn = ct[m][r] * sigm(zf + 1.0f) + sigm(zi) * ftanh(zj);
                ct[m][r] = cn;
                float h = ftanh(cn) * sigm(zo);
                // Hs image of the frag: [m][cell>>3][row16][cell&7]
                Hs[hsw + (m << 8) + (((lane >> 3) & 1) << 7) + (row16 << 3) + (lane & 7)] = f2h(h);
                if (t == SEQ - 1) {
                    int row = r0 + wv * 32 + m * 16 + row16;
                    hf32[(size_t)row * NCELL + cell] = h;
                }
            }
        }
        // read back (2-way-aliased b128, free) and store two half-frags per wave
        {
            u16x8 v = *(const u16x8*)&Hs[hsw + lane * 8];
            st128(&Np[esto], v);
        }
        // Stage next step's x-slice into the next A plane (fragment-major).
        if (t + 1 < SEQ && nb < NFEAT && tid < 128) {
            int row = r0 + tid;
            float v = X[(size_t)row * (SEQ * NFEAT) + (t + 1) * NFEAT + nb];
            int wv2 = tid >> 5, m2 = (tid >> 4) & 1;
            int elane2 = (tid & 15) | ((nb >> 3) << 4);
            u32 idx = (u32)(((rb * 4 + wv2) * NCH + 16) * 2 + m2) * 512u
                    + (u32)(elane2 * 8 + (nb & 7));
            st16(&Np[idx], (u32)f2h(v));
        }

        // ---- row-group barrier: pure atomics, NO cache maintenance ----
        __syncthreads();   // vmcnt drained: write-through stores visible at L3
        if (tid == 0) {
            int n = __hip_atomic_fetch_add(bcnt, 1, __ATOMIC_RELAXED, __HIP_MEMORY_SCOPE_AGENT);
            if (n == GWG - 1) {
                __hip_atomic_store(bcnt, 0, __ATOMIC_RELAXED, __HIP_MEMORY_SCOPE_AGENT);
                // RELAXED: data already at coherence point (write-through + vmcnt drain);
                // avoids the L2-writeback scan an agent RELEASE would emit.
                __hip_atomic_store(bepoch, t + 1, __ATOMIC_RELAXED, __HIP_MEMORY_SCOPE_AGENT);
            } else {
                int spins = 0;
                while (__hip_atomic_load(bepoch, __ATOMIC_RELAXED, __HIP_MEMORY_SCOPE_AGENT) <= t) {
                    __builtin_amdgcn_s_sleep(4);
                    if (++spins > 20000000) break;   // bail out instead of hanging
                }
            }
        }
        __syncthreads();
        // no fence: next step's H reads are read-through atomics (always coherent)
    }
}

// ---------- fp32 tail GEMM: C = act(A @ Wm + bias), tile 64x64 ----------
template <int ACT>
__global__ __launch_bounds__(256) void gemm64(
    const float* __restrict__ A, const float* __restrict__ Wm,
    const float* __restrict__ bias, float* __restrict__ out,
    int M, int N, int K)
{
    __shared__ float Asf[32][65];
    __shared__ float Bsf[32][65];
    const int c0 = blockIdx.x * 64;
    const int r0 = blockIdx.y * 64;
    const int tid = (int)threadIdx.x;
    const int tx = tid & 15, ty = tid >> 4;

    float acc[4][4];
    #pragma unroll
    for (int r = 0; r < 4; ++r) { acc[r][0]=0.f; acc[r][1]=0.f; acc[r][2]=0.f; acc[r][3]=0.f; }

    for (int k0 = 0; k0 < K; k0 += 32) {
        #pragma unroll
        for (int i = 0; i < 8; ++i) {
            int e = tid + 256 * i;
            int row = e >> 5, kk = e & 31;
            Asf[kk][row] = A[(size_t)(r0 + row) * K + k0 + kk];
        }
        #pragma unroll
        for (int i = 0; i < 8; ++i) {
            int e = tid + 256 * i;
            int kk = e >> 6, cl = e & 63;
            Bsf[kk][cl] = Wm[(size_t)(k0 + kk) * N + c0 + cl];
        }
        __syncthreads();
        #pragma unroll
        for (int kk = 0; kk < 32; ++kk) {
            float b0 = Bsf[kk][tx*4], b1 = Bsf[kk][tx*4+1], b2 = Bsf[kk][tx*4+2], b3 = Bsf[kk][tx*4+3];
            #pragma unroll
            for (int r = 0; r < 4; ++r) {
                float a = Asf[kk][ty*4 + r];
                acc[r][0] = fmaf(a, b0, acc[r][0]);
                acc[r][1] = fmaf(a, b1, acc[r][1]);
                acc[r][2] = fmaf(a, b2, acc[r][2]);
                acc[r][3] = fmaf(a, b3, acc[r][3]);
            }
        }
        __syncthreads();
    }
    #pragma unroll
    for (int r = 0; r < 4; ++r) {
        int gr = r0 + ty * 4 + r;
        #pragma unroll
        for (int j = 0; j < 4; ++j) {
            int gc = c0 + tx * 4 + j;
            float v = acc[r][j] + bias[gc];
            if (ACT) v = fmaxf(v, 0.f);
            out[(size_t)gr * N + gc] = v;
        }
    }
}

extern "C" void kernel_launch(void* const* d_in, const int* in_sizes, int n_in,
                              void* d_out, int out_size, void* d_ws, size_t ws_size,
                              hipStream_t stream)
{
    const float* X  = (const float*)d_in[0];
    const float* Wl = (const float*)d_in[1];
    const float* bl = (const float*)d_in[2];
    const float* Wd = (const float*)d_in[3];
    const float* bd = (const float*)d_in[4];
    const float* Wp = (const float*)d_in[5];
    const float* bp = (const float*)d_in[6];
    float* out = (float*)d_out;

    // ws layout
    char* p = (char*)d_ws;
    int* bar      = (int*)p; p += 4096;                              // 8 groups x 256 B
    float* hf32   = (float*)p; p += (size_t)BATCH * NCELL * 4;       // 2 MB
    float* dense  = (float*)p; p += (size_t)BATCH * DENSE_N * 4;     // 8 MB
    u16* Wt   = (u16*)p; p += (size_t)ZC * KP * 2;                   // 2.23 MB fp16
    u16* H0   = (u16*)p; p += (size_t)BATCH * KP * 2;                // 1.11 MB
    u16* H1   = (u16*)p; p += (size_t)BATCH * KP * 2;

    (void)hipMemsetAsync(bar, 0, 4096, stream);
    prep_w<<<(ZC * KP) / 256, 256, 0, stream>>>(Wl, Wt);
    prep_h<<<(BATCH * KP) / 256, 256, 0, stream>>>(X, H0, H1);

    const int lds_bytes = 64 * KL * 2 + 4 * 512 * 2;   // 73728 + 4096 = 77824
    (void)hipFuncSetAttribute((const void*)lstm_persist,
                              hipFuncAttributeMaxDynamicSharedMemorySize, lds_bytes);
    lstm_persist<<<NWG, 256, lds_bytes, stream>>>(H0, H1, Wt, bl, X, hf32, bar);

    dim3 blk(256);
    gemm64<1><<<dim3(DENSE_N / 64, BATCH / 64), blk, 0, stream>>>(hf32, Wd, bd, dense, BATCH, DENSE_N, NCELL);
    gemm64<0><<<dim3(PRED_N / 64, BATCH / 64), blk, 0, stream>>>(dense, Wp, bp, out, BATCH, PRED_N, DENSE_N);
}